// Round 4
// baseline (3144.880 us; speedup 1.0000x reference)
//
#include <hip/hip_runtime.h>
#include <hip/hip_bf16.h>

#define FDIM 128
#define HDIM 128
#define ADIM 32
#define PCH 128   // rows per pool block
#define BSH 6     // bucket shift: 64 dst nodes per bucket
#define BWD 64    // bucket width

// bf16x2 helpers (bitwise; bf16->fp32 exact, fp32->bf16 RNE)
static __device__ __forceinline__ float bflo(unsigned int u) {
    return __builtin_bit_cast(float, u << 16);
}
static __device__ __forceinline__ float bfhi(unsigned int u) {
    return __builtin_bit_cast(float, u & 0xffff0000u);
}
static __device__ __forceinline__ unsigned int bfpack(float a, float b) {
    unsigned int ua = __builtin_bit_cast(unsigned int, a);
    unsigned int ub = __builtin_bit_cast(unsigned int, b);
    ua += 0x7fffu + ((ua >> 16) & 1u);
    ub += 0x7fffu + ((ub >> 16) & 1u);
    return (ua >> 16) | (ub & 0xffff0000u);
}

// ---------------------------------------------------------------------------
// Degree + bucket histogram in one pass over dst
__global__ void hist_kernel(const int* __restrict__ dst, int* __restrict__ deg,
                            int* __restrict__ bhist, int E) {
    int e = blockIdx.x * 256 + threadIdx.x;
    if (e < E) {
        int d = dst[e];
        atomicAdd(&deg[d], 1);
        atomicAdd(&bhist[d >> BSH], 1);
    }
}

__global__ void dinv_kernel(const int* __restrict__ deg, float* __restrict__ dinv, int n) {
    int i = blockIdx.x * 256 + threadIdx.x;
    if (i < n) dinv[i] = rsqrtf((float)deg[i] + 1.0f);
}

// Single-block exclusive scan of bhist (NB <= 2048) -> bptr and bcur
__global__ void bscan(const int* __restrict__ bhist, int* __restrict__ bptr,
                      int* __restrict__ bcur, int NB, int E) {
    __shared__ int tmp[256];
    const int t = threadIdx.x;
    int v[8], s = 0;
    #pragma unroll
    for (int i = 0; i < 8; ++i) { int j = t * 8 + i; v[i] = (j < NB) ? bhist[j] : 0; s += v[i]; }
    tmp[t] = s;
    __syncthreads();
    for (int off = 1; off < 256; off <<= 1) {
        int x = (t >= off) ? tmp[t - off] : 0;
        __syncthreads();
        tmp[t] += x;
        __syncthreads();
    }
    int run = tmp[t] - s;
    #pragma unroll
    for (int i = 0; i < 8; ++i) {
        int j = t * 8 + i;
        if (j < NB) { bptr[j] = run; bcur[j] = run; }
        run += v[i];
    }
    if (t == 255) bptr[NB] = E;
}

// Append (src,dst) pairs into bucket segments (L2-friendly sequential appends)
__global__ void bucket_fill(const int* __restrict__ src, const int* __restrict__ dst,
                            int* __restrict__ bcur, uint2* __restrict__ pairs, int E) {
    int e = blockIdx.x * 256 + threadIdx.x;
    if (e >= E) return;
    int s = src[e], d = dst[e];
    int pos = atomicAdd(&bcur[d >> BSH], 1);
    pairs[pos] = make_uint2((unsigned)s, (unsigned)d);
}

// ---------------------------------------------------------------------------
// GEMM + row-scale epilogue, bf16 output: Out[r] = bf16((X[r] @ W) * rowscale[r])
// X is fp32 (layer 1) or bf16 (layer 2).
template <bool BF16IN>
__global__ __launch_bounds__(256, 2) void gemm128(const void* __restrict__ Xv,
                                                  const float* __restrict__ W,
                                                  const float* __restrict__ rowscale,
                                                  uint2* __restrict__ Out, int n) {
    __shared__ float sW[64 * 128];
    __shared__ float sX[32 * 128];
    const int tid = threadIdx.x;
    const int rbase = blockIdx.x * 32;
    int rows = n - rbase; if (rows > 32) rows = 32;

    if (BF16IN) {
        const uint2* X2 = (const uint2*)((const unsigned short*)Xv + (size_t)rbase * 128);
        float4* sX4 = (float4*)sX;
        for (int i = tid; i < rows * 32; i += 256) {
            uint2 u = X2[i];
            sX4[i] = make_float4(bflo(u.x), bfhi(u.x), bflo(u.y), bfhi(u.y));
        }
    } else {
        const float4* X4 = (const float4*)((const float*)Xv + (size_t)rbase * 128);
        float4* sX4 = (float4*)sX;
        for (int i = tid; i < rows * 32; i += 256) sX4[i] = X4[i];
    }

    const int tx = tid & 31;
    const int ty = tid >> 5;
    float acc[4][4] = {{0.f,0.f,0.f,0.f},{0.f,0.f,0.f,0.f},{0.f,0.f,0.f,0.f},{0.f,0.f,0.f,0.f}};

    for (int half = 0; half < 2; ++half) {
        __syncthreads();
        {
            const float4* W4 = (const float4*)(W + half * 64 * 128);
            float4* sW4 = (float4*)sW;
            for (int i = tid; i < 2048; i += 256) sW4[i] = W4[i];
        }
        __syncthreads();

        const float* xb = sX + ty * 4 * 128 + half * 64;
        #pragma unroll 8
        for (int kk = 0; kk < 64; ++kk) {
            const float4 w = *(const float4*)(sW + kk * 128 + tx * 4);
            float xv[4];
            #pragma unroll
            for (int i = 0; i < 4; ++i) xv[i] = xb[i * 128 + kk];
            #pragma unroll
            for (int i = 0; i < 4; ++i) {
                acc[i][0] = fmaf(xv[i], w.x, acc[i][0]);
                acc[i][1] = fmaf(xv[i], w.y, acc[i][1]);
                acc[i][2] = fmaf(xv[i], w.z, acc[i][2]);
                acc[i][3] = fmaf(xv[i], w.w, acc[i][3]);
            }
        }
    }

    #pragma unroll
    for (int i = 0; i < 4; ++i) {
        int r = rbase + ty * 4 + i;
        if (r < n) {
            float sc = rowscale[r];
            unsigned int p0 = bfpack(acc[i][0] * sc, acc[i][1] * sc);
            unsigned int p1 = bfpack(acc[i][2] * sc, acc[i][3] * sc);
            Out[(size_t)r * 32 + tx] = make_uint2(p0, p1);
        }
    }
}

// ---------------------------------------------------------------------------
// Fused bucket gather + GCN epilogue on pre-scaled bf16 T' = (X@W)*dinv[row]:
//   h[d] = relu( (sum_{s in in(d)} T'[s] + T'[d]) * dinv[d] + bias )
// One block per bucket of 64 dst nodes; 64-node x 128-col fp32 accumulator in LDS.
__global__ __launch_bounds__(256) void bgather(const unsigned int* __restrict__ T,  // bf16x2, 64/row
                                               const uint2* __restrict__ pairs,
                                               const int* __restrict__ bptr,
                                               const float* __restrict__ dinv,
                                               const float* __restrict__ bias,
                                               unsigned int* __restrict__ H, int n) {
    __shared__ float acc[BWD * 128];  // 32 KB
    const int tid = threadIdx.x;
    for (int i = tid; i < BWD * 128; i += 256) acc[i] = 0.f;
    __syncthreads();

    const int b = blockIdx.x;
    const int w = tid >> 6, l = tid & 63;
    const int start = bptr[b], end = bptr[b + 1];
    for (int e = start + w; e < end; e += 4) {
        uint2 p = pairs[e];
        unsigned int u = T[(size_t)p.x * 64 + l];
        float* ap = acc + (((int)p.y & (BWD - 1)) << 7) + (l << 1);
        atomicAdd(ap, bflo(u));
        atomicAdd(ap + 1, bfhi(u));
    }
    __syncthreads();

    const float2 bv = ((const float2*)bias)[l];
    for (int j = w; j < BWD; j += 4) {
        int node = (b << BSH) + j;
        if (node >= n) break;
        unsigned int su = T[(size_t)node * 64 + l];
        float vx = acc[(j << 7) + (l << 1)] + bflo(su);
        float vy = acc[(j << 7) + (l << 1) + 1] + bfhi(su);
        float di = dinv[node];
        float ox = fmaxf(fmaf(vx, di, bv.x), 0.f);
        float oy = fmaxf(fmaf(vy, di, bv.y), 0.f);
        H[(size_t)node * 64 + l] = bfpack(ox, oy);
    }
}

// ---------------------------------------------------------------------------
__global__ void graph_bounds(const int* __restrict__ batch, int* __restrict__ gstart,
                             int n, int G) {
    int g = blockIdx.x * 128 + threadIdx.x;
    if (g > G) return;
    int lo = 0, hi = n;
    while (lo < hi) { int mid = (lo + hi) >> 1; if (batch[mid] < g) lo = mid + 1; else hi = mid; }
    gstart[g] = lo;
}

// Parallel partial-sum pool over bf16 h (batch sorted -> per-thread running acc)
__global__ __launch_bounds__(256) void pool_partial(const unsigned short* __restrict__ h,
                                                    const int* __restrict__ batch,
                                                    float* __restrict__ pooled, int n) {
    const int c = threadIdx.x & 127;
    const int half = threadIdx.x >> 7;
    int r = blockIdx.x * PCH + half;
    int rend = blockIdx.x * PCH + PCH;
    if (rend > n) rend = n;
    float acc = 0.f;
    int cur = -1;
    for (; r < rend; r += 2) {
        int g = batch[r];
        if (g != cur) {
            if (cur >= 0) atomicAdd(&pooled[(size_t)cur * 128 + c], acc);
            acc = 0.f;
            cur = g;
        }
        acc += __builtin_bit_cast(float, (unsigned int)h[(size_t)r * 128 + c] << 16);
    }
    if (cur >= 0) atomicAdd(&pooled[(size_t)cur * 128 + c], acc);
}

// ---------------------------------------------------------------------------
// out layout: [G*A action_mean][A std][G value]; divides pooled sums by count
__global__ void head_kernel(const float* __restrict__ pooled, const int* __restrict__ gstart,
                            const float* __restrict__ Wa, const float* __restrict__ ba,
                            const float* __restrict__ Wv, const float* __restrict__ bv,
                            const float* __restrict__ log_std, float* __restrict__ out, int G) {
    int g = blockIdx.x;
    int t = threadIdx.x;  // 64
    __shared__ float sp[128];
    float inv = 1.0f / fmaxf((float)(gstart[g + 1] - gstart[g]), 1.0f);
    sp[t] = pooled[(size_t)g * 128 + t] * inv;
    sp[t + 64] = pooled[(size_t)g * 128 + 64 + t] * inv;
    __syncthreads();
    if (t < 32) {
        float s = 0.f;
        #pragma unroll 8
        for (int k = 0; k < 128; ++k) s = fmaf(sp[k], Wa[k * ADIM + t], s);
        out[g * ADIM + t] = s + ba[t];
        if (g == 0) out[G * ADIM + t] = expf(log_std[t]);
    } else if (t == 32) {
        float s = 0.f;
        #pragma unroll 8
        for (int k = 0; k < 128; ++k) s = fmaf(sp[k], Wv[k], s);
        out[G * ADIM + ADIM + g] = s + bv[0];
    }
}

// ---------------------------------------------------------------------------
extern "C" void kernel_launch(void* const* d_in, const int* in_sizes, int n_in,
                              void* d_out, int out_size, void* d_ws, size_t ws_size,
                              hipStream_t stream) {
    const float* x       = (const float*)d_in[0];
    const int*   ei      = (const int*)d_in[1];
    const int*   batch   = (const int*)d_in[2];
    const float* W1      = (const float*)d_in[3];
    const float* b1      = (const float*)d_in[4];
    const float* W2      = (const float*)d_in[5];
    const float* b2      = (const float*)d_in[6];
    const float* Wa      = (const float*)d_in[7];
    const float* ba      = (const float*)d_in[8];
    const float* Wv      = (const float*)d_in[9];
    const float* bv      = (const float*)d_in[10];
    const float* log_std = (const float*)d_in[11];
    float* out = (float*)d_out;

    const int N = in_sizes[0] / FDIM;
    const int E = in_sizes[1] / 2;
    const int G = (out_size - ADIM) / (ADIM + 1);
    const int NB = (N + BWD - 1) >> BSH;  // buckets (<= 2048 for N <= 128K)

    const int* src = ei;
    const int* dst = ei + E;

    auto align = [](size_t v) { return (v + 255) & ~(size_t)255; };
    char* ws = (char*)d_ws;
    size_t off = 0;
    int*   deg_i  = (int*)(ws + off);   off += (size_t)N * 4;           // deg + bhist contiguous
    int*   bhist  = (int*)(ws + off);   off = align(off + (size_t)(NB + 1) * 4);
    int*   bptr   = (int*)(ws + off);   off = align(off + (size_t)(NB + 1) * 4);
    int*   bcur   = (int*)(ws + off);   off = align(off + (size_t)NB * 4);
    int*   gstart = (int*)(ws + off);   off = align(off + (size_t)(G + 1) * 4);
    float* dinv   = (float*)(ws + off); off = align(off + (size_t)N * 4);
    float* pooled = (float*)(ws + off); off = align(off + (size_t)G * HDIM * 4);
    uint2* pairs  = (uint2*)(ws + off); off = align(off + (size_t)E * 8);
    unsigned int* bufA = (unsigned int*)(ws + off); off = align(off + (size_t)N * 64 * 4);  // bf16 N x 128
    unsigned int* bufB = (unsigned int*)(ws + off); off = align(off + (size_t)N * 64 * 4);
    (void)ws_size;

    const int blkE = (E + 255) / 256;
    const int blkN = (N + 255) / 256;
    const int blkGemm = (N + 31) / 32;
    const int blkPool = (N + PCH - 1) / PCH;

    // ---- binning + dinv ----
    hipMemsetAsync(deg_i, 0, ((size_t)N + NB + 1) * 4, stream);
    hist_kernel<<<blkE, 256, 0, stream>>>(dst, deg_i, bhist, E);
    dinv_kernel<<<blkN, 256, 0, stream>>>(deg_i, dinv, N);
    bscan<<<1, 256, 0, stream>>>(bhist, bptr, bcur, NB, E);
    bucket_fill<<<blkE, 256, 0, stream>>>(src, dst, bcur, pairs, E);
    graph_bounds<<<1, 128, 0, stream>>>(batch, gstart, N, G);

    // ---- layer 1 (fp32 in, bf16 out) ----
    gemm128<false><<<blkGemm, 256, 0, stream>>>(x, W1, dinv, (uint2*)bufA, N);
    bgather<<<NB, 256, 0, stream>>>(bufA, pairs, bptr, dinv, b1, bufB, N);

    // ---- layer 2 (bf16 in, bf16 out) ----
    gemm128<true><<<blkGemm, 256, 0, stream>>>(bufB, W2, dinv, (uint2*)bufA, N);
    bgather<<<NB, 256, 0, stream>>>(bufA, pairs, bptr, dinv, b2, bufB, N);

    // ---- pool + heads ----
    hipMemsetAsync(pooled, 0, (size_t)G * HDIM * 4, stream);
    pool_partial<<<blkPool, 256, 0, stream>>>((const unsigned short*)bufB, batch, pooled, N);
    head_kernel<<<G, 64, 0, stream>>>(pooled, gstart, Wa, ba, Wv, bv, log_std, out, G);
}

// Round 5
// 1000.856 us; speedup vs baseline: 3.1422x; 3.1422x over previous
//
#include <hip/hip_runtime.h>
#include <hip/hip_bf16.h>

#define FDIM 128
#define HDIM 128
#define ADIM 32
#define PCH 128   // rows per pool block
#define BSH 6     // bucket shift: 64 dst nodes per bucket
#define BWD 64

// bf16x2 helpers (bitwise; bf16->fp32 exact, fp32->bf16 RNE)
static __device__ __forceinline__ float bflo(unsigned int u) {
    return __builtin_bit_cast(float, u << 16);
}
static __device__ __forceinline__ float bfhi(unsigned int u) {
    return __builtin_bit_cast(float, u & 0xffff0000u);
}
static __device__ __forceinline__ unsigned int bfpack(float a, float b) {
    unsigned int ua = __builtin_bit_cast(unsigned int, a);
    unsigned int ub = __builtin_bit_cast(unsigned int, b);
    ua += 0x7fffu + ((ua >> 16) & 1u);
    ub += 0x7fffu + ((ub >> 16) & 1u);
    return (ua >> 16) | (ub & 0xffff0000u);
}

// ---------------------------------------------------------------------------
// Degree + bucket histogram in one pass over dst
__global__ void hist_kernel(const int* __restrict__ dst, int* __restrict__ deg,
                            int* __restrict__ bhist, int E) {
    int e = blockIdx.x * 256 + threadIdx.x;
    if (e < E) {
        int d = dst[e];
        atomicAdd(&deg[d], 1);
        atomicAdd(&bhist[d >> BSH], 1);
    }
}

__global__ void dinv_kernel(const int* __restrict__ deg, float* __restrict__ dinv, int n) {
    int i = blockIdx.x * 256 + threadIdx.x;
    if (i < n) dinv[i] = rsqrtf((float)deg[i] + 1.0f);
}

// ---------------------------------------------------------------------------
// Exclusive scan of deg -> rowptr (per-node CSR). 1024 items/block.
__global__ void scan1(const int* __restrict__ deg, int* __restrict__ excl,
                      int* __restrict__ bsum, int n) {
    __shared__ int tmp[256];
    const int t = threadIdx.x;
    const int idx = blockIdx.x * 1024 + t * 4;
    int v[4], s = 0;
    #pragma unroll
    for (int i = 0; i < 4; ++i) { int j = idx + i; v[i] = (j < n) ? deg[j] : 0; s += v[i]; }
    tmp[t] = s;
    __syncthreads();
    for (int off = 1; off < 256; off <<= 1) {
        int x = (t >= off) ? tmp[t - off] : 0;
        __syncthreads();
        tmp[t] += x;
        __syncthreads();
    }
    int run = tmp[t] - s;
    #pragma unroll
    for (int i = 0; i < 4; ++i) { int j = idx + i; if (j < n) excl[j] = run; run += v[i]; }
    if (t == 255) bsum[blockIdx.x] = tmp[255];
}

__global__ void scan2(int* __restrict__ bsum, int nb) {
    __shared__ int tmp[256];
    const int t = threadIdx.x;
    int s = (t < nb) ? bsum[t] : 0;
    tmp[t] = s;
    __syncthreads();
    for (int off = 1; off < 256; off <<= 1) {
        int x = (t >= off) ? tmp[t - off] : 0;
        __syncthreads();
        tmp[t] += x;
        __syncthreads();
    }
    if (t < nb) bsum[t] = tmp[t] - s;
}

__global__ void scan3(int* __restrict__ excl, const int* __restrict__ bsum,
                      int* __restrict__ cursor, int n, int E) {
    int i = blockIdx.x * 256 + threadIdx.x;
    if (i < n) {
        int v = excl[i] + bsum[blockIdx.x >> 2];
        excl[i] = v;
        cursor[i] = v;
    }
    if (i == 0) excl[n] = E;
}

// Single-block exclusive scan of bhist (NB <= 2048) -> bucket cursors
__global__ void bscan(const int* __restrict__ bhist, int* __restrict__ bcur, int NB) {
    __shared__ int tmp[256];
    const int t = threadIdx.x;
    int v[8], s = 0;
    #pragma unroll
    for (int i = 0; i < 8; ++i) { int j = t * 8 + i; v[i] = (j < NB) ? bhist[j] : 0; s += v[i]; }
    tmp[t] = s;
    __syncthreads();
    for (int off = 1; off < 256; off <<= 1) {
        int x = (t >= off) ? tmp[t - off] : 0;
        __syncthreads();
        tmp[t] += x;
        __syncthreads();
    }
    int run = tmp[t] - s;
    #pragma unroll
    for (int i = 0; i < 8; ++i) {
        int j = t * 8 + i;
        if (j < NB) bcur[j] = run;
        run += v[i];
    }
}

// Level 1: append (src,dst) pairs into bucket segments (L2-friendly appends)
__global__ void bucket_fill(const int* __restrict__ src, const int* __restrict__ dst,
                            int* __restrict__ bcur, uint2* __restrict__ pairs, int E) {
    int e = blockIdx.x * 256 + threadIdx.x;
    if (e >= E) return;
    int s = src[e], d = dst[e];
    int pos = atomicAdd(&bcur[d >> BSH], 1);
    pairs[pos] = make_uint2((unsigned)s, (unsigned)d);
}

// Level 2: bucket-grouped pairs -> per-node CSR col. Each warp's writes land in
// a ~4KB window of col (one bucket), so write-back stays dense in L2.
__global__ void csr_from_buckets(const uint2* __restrict__ pairs,
                                 int* __restrict__ cursor, int* __restrict__ col, int E) {
    int e = blockIdx.x * 256 + threadIdx.x;
    if (e >= E) return;
    uint2 p = pairs[e];
    int pos = atomicAdd(&cursor[p.y], 1);
    col[pos] = (int)p.x;
}

// ---------------------------------------------------------------------------
// GEMM + row-scale epilogue, bf16 output: Out[r] = bf16((X[r] @ W) * rowscale[r])
template <bool BF16IN>
__global__ __launch_bounds__(256, 2) void gemm128(const void* __restrict__ Xv,
                                                  const float* __restrict__ W,
                                                  const float* __restrict__ rowscale,
                                                  uint2* __restrict__ Out, int n) {
    __shared__ float sW[64 * 128];
    __shared__ float sX[32 * 128];
    const int tid = threadIdx.x;
    const int rbase = blockIdx.x * 32;
    int rows = n - rbase; if (rows > 32) rows = 32;

    if (BF16IN) {
        const uint2* X2 = (const uint2*)((const unsigned short*)Xv + (size_t)rbase * 128);
        float4* sX4 = (float4*)sX;
        for (int i = tid; i < rows * 32; i += 256) {
            uint2 u = X2[i];
            sX4[i] = make_float4(bflo(u.x), bfhi(u.x), bflo(u.y), bfhi(u.y));
        }
    } else {
        const float4* X4 = (const float4*)((const float*)Xv + (size_t)rbase * 128);
        float4* sX4 = (float4*)sX;
        for (int i = tid; i < rows * 32; i += 256) sX4[i] = X4[i];
    }

    const int tx = tid & 31;
    const int ty = tid >> 5;
    float acc[4][4] = {{0.f,0.f,0.f,0.f},{0.f,0.f,0.f,0.f},{0.f,0.f,0.f,0.f},{0.f,0.f,0.f,0.f}};

    for (int half = 0; half < 2; ++half) {
        __syncthreads();
        {
            const float4* W4 = (const float4*)(W + half * 64 * 128);
            float4* sW4 = (float4*)sW;
            for (int i = tid; i < 2048; i += 256) sW4[i] = W4[i];
        }
        __syncthreads();

        const float* xb = sX + ty * 4 * 128 + half * 64;
        #pragma unroll 8
        for (int kk = 0; kk < 64; ++kk) {
            const float4 w = *(const float4*)(sW + kk * 128 + tx * 4);
            float xv[4];
            #pragma unroll
            for (int i = 0; i < 4; ++i) xv[i] = xb[i * 128 + kk];
            #pragma unroll
            for (int i = 0; i < 4; ++i) {
                acc[i][0] = fmaf(xv[i], w.x, acc[i][0]);
                acc[i][1] = fmaf(xv[i], w.y, acc[i][1]);
                acc[i][2] = fmaf(xv[i], w.z, acc[i][2]);
                acc[i][3] = fmaf(xv[i], w.w, acc[i][3]);
            }
        }
    }

    #pragma unroll
    for (int i = 0; i < 4; ++i) {
        int r = rbase + ty * 4 + i;
        if (r < n) {
            float sc = rowscale[r];
            unsigned int p0 = bfpack(acc[i][0] * sc, acc[i][1] * sc);
            unsigned int p1 = bfpack(acc[i][2] * sc, acc[i][3] * sc);
            Out[(size_t)r * 32 + tx] = make_uint2(p0, p1);
        }
    }
}

// ---------------------------------------------------------------------------
// Fused CSR gather + epilogue on pre-scaled bf16 T' = (X@W)*dinv[row]:
//   h[d] = relu( (sum_{s in in(d)} T'[s] + T'[d]) * dinv[d] + bias )
// One wave per destination node, register accumulation; lane covers 2 cols.
__global__ __launch_bounds__(256) void gather_fused(const unsigned int* __restrict__ T,
                                                    const int* __restrict__ rowptr,
                                                    const int* __restrict__ col,
                                                    const float* __restrict__ dinv,
                                                    const float* __restrict__ bias,
                                                    unsigned int* __restrict__ H, int n) {
    const int d = (blockIdx.x * 256 + threadIdx.x) >> 6;
    const int lane = threadIdx.x & 63;
    if (d >= n) return;
    int e = rowptr[d];
    const int end = rowptr[d + 1];

    float ax = 0.f, ay = 0.f, bx = 0.f, by = 0.f;
    for (; e + 3 < end; e += 4) {
        int s0 = col[e], s1 = col[e + 1], s2 = col[e + 2], s3 = col[e + 3];
        unsigned int u0 = T[(size_t)s0 * 64 + lane];
        unsigned int u1 = T[(size_t)s1 * 64 + lane];
        unsigned int u2 = T[(size_t)s2 * 64 + lane];
        unsigned int u3 = T[(size_t)s3 * 64 + lane];
        ax += bflo(u0) + bflo(u1); ay += bfhi(u0) + bfhi(u1);
        bx += bflo(u2) + bflo(u3); by += bfhi(u2) + bfhi(u3);
    }
    for (; e < end; ++e) {
        unsigned int u = T[(size_t)col[e] * 64 + lane];
        ax += bflo(u); ay += bfhi(u);
    }

    unsigned int su = T[(size_t)d * 64 + lane];
    const float di = dinv[d];
    const float2 bv = ((const float2*)bias)[lane];
    float ox = fmaxf(fmaf(ax + bx + bflo(su), di, bv.x), 0.f);
    float oy = fmaxf(fmaf(ay + by + bfhi(su), di, bv.y), 0.f);
    H[(size_t)d * 64 + lane] = bfpack(ox, oy);
}

// ---------------------------------------------------------------------------
__global__ void graph_bounds(const int* __restrict__ batch, int* __restrict__ gstart,
                             int n, int G) {
    int g = blockIdx.x * 128 + threadIdx.x;
    if (g > G) return;
    int lo = 0, hi = n;
    while (lo < hi) { int mid = (lo + hi) >> 1; if (batch[mid] < g) lo = mid + 1; else hi = mid; }
    gstart[g] = lo;
}

// Parallel partial-sum pool over bf16 h (batch sorted -> per-thread running acc)
__global__ __launch_bounds__(256) void pool_partial(const unsigned short* __restrict__ h,
                                                    const int* __restrict__ batch,
                                                    float* __restrict__ pooled, int n) {
    const int c = threadIdx.x & 127;
    const int half = threadIdx.x >> 7;
    int r = blockIdx.x * PCH + half;
    int rend = blockIdx.x * PCH + PCH;
    if (rend > n) rend = n;
    float acc = 0.f;
    int cur = -1;
    for (; r < rend; r += 2) {
        int g = batch[r];
        if (g != cur) {
            if (cur >= 0) atomicAdd(&pooled[(size_t)cur * 128 + c], acc);
            acc = 0.f;
            cur = g;
        }
        acc += __builtin_bit_cast(float, (unsigned int)h[(size_t)r * 128 + c] << 16);
    }
    if (cur >= 0) atomicAdd(&pooled[(size_t)cur * 128 + c], acc);
}

// ---------------------------------------------------------------------------
// out layout: [G*A action_mean][A std][G value]
__global__ void head_kernel(const float* __restrict__ pooled, const int* __restrict__ gstart,
                            const float* __restrict__ Wa, const float* __restrict__ ba,
                            const float* __restrict__ Wv, const float* __restrict__ bv,
                            const float* __restrict__ log_std, float* __restrict__ out, int G) {
    int g = blockIdx.x;
    int t = threadIdx.x;  // 64
    __shared__ float sp[128];
    float inv = 1.0f / fmaxf((float)(gstart[g + 1] - gstart[g]), 1.0f);
    sp[t] = pooled[(size_t)g * 128 + t] * inv;
    sp[t + 64] = pooled[(size_t)g * 128 + 64 + t] * inv;
    __syncthreads();
    if (t < 32) {
        float s = 0.f;
        #pragma unroll 8
        for (int k = 0; k < 128; ++k) s = fmaf(sp[k], Wa[k * ADIM + t], s);
        out[g * ADIM + t] = s + ba[t];
        if (g == 0) out[G * ADIM + t] = expf(log_std[t]);
    } else if (t == 32) {
        float s = 0.f;
        #pragma unroll 8
        for (int k = 0; k < 128; ++k) s = fmaf(sp[k], Wv[k], s);
        out[G * ADIM + ADIM + g] = s + bv[0];
    }
}

// ---------------------------------------------------------------------------
extern "C" void kernel_launch(void* const* d_in, const int* in_sizes, int n_in,
                              void* d_out, int out_size, void* d_ws, size_t ws_size,
                              hipStream_t stream) {
    const float* x       = (const float*)d_in[0];
    const int*   ei      = (const int*)d_in[1];
    const int*   batch   = (const int*)d_in[2];
    const float* W1      = (const float*)d_in[3];
    const float* b1      = (const float*)d_in[4];
    const float* W2      = (const float*)d_in[5];
    const float* b2      = (const float*)d_in[6];
    const float* Wa      = (const float*)d_in[7];
    const float* ba      = (const float*)d_in[8];
    const float* Wv      = (const float*)d_in[9];
    const float* bv      = (const float*)d_in[10];
    const float* log_std = (const float*)d_in[11];
    float* out = (float*)d_out;

    const int N = in_sizes[0] / FDIM;
    const int E = in_sizes[1] / 2;
    const int G = (out_size - ADIM) / (ADIM + 1);
    const int NB = (N + BWD - 1) >> BSH;

    const int* src = ei;
    const int* dst = ei + E;

    auto align = [](size_t v) { return (v + 255) & ~(size_t)255; };
    char* ws = (char*)d_ws;
    size_t off = 0;
    int*   deg_i  = (int*)(ws + off);   off += (size_t)N * 4;            // deg + bhist zeroed together
    int*   bhist  = (int*)(ws + off);   off = align(off + (size_t)(NB + 1) * 4);
    int*   rowptr = (int*)(ws + off);   off = align(off + (size_t)(N + 1) * 4);
    int*   cursor = (int*)(ws + off);   off = align(off + (size_t)N * 4);
    int*   bcur   = (int*)(ws + off);   off = align(off + (size_t)NB * 4);
    int*   bsum   = (int*)(ws + off);   off = align(off + (size_t)256 * 4);
    int*   gstart = (int*)(ws + off);   off = align(off + (size_t)(G + 1) * 4);
    float* dinv   = (float*)(ws + off); off = align(off + (size_t)N * 4);
    float* pooled = (float*)(ws + off); off = align(off + (size_t)G * HDIM * 4);
    uint2* pairs  = (uint2*)(ws + off); off = align(off + (size_t)E * 8);
    int*   col    = (int*)(ws + off);   off = align(off + (size_t)E * 4);
    unsigned int* bufA = (unsigned int*)(ws + off); off = align(off + (size_t)N * 64 * 4);
    unsigned int* bufB = (unsigned int*)(ws + off); off = align(off + (size_t)N * 64 * 4);
    (void)ws_size;

    const int blkE = (E + 255) / 256;
    const int blkN = (N + 255) / 256;
    const int nb   = (N + 1023) / 1024;
    const int blkGemm = (N + 31) / 32;
    const int blkGather = (int)(((long long)N * 64 + 255) / 256);
    const int blkPool = (N + PCH - 1) / PCH;

    // ---- binning + CSR + dinv ----
    hipMemsetAsync(deg_i, 0, ((size_t)N + NB + 1) * 4, stream);
    hist_kernel<<<blkE, 256, 0, stream>>>(dst, deg_i, bhist, E);
    dinv_kernel<<<blkN, 256, 0, stream>>>(deg_i, dinv, N);
    scan1<<<nb, 256, 0, stream>>>(deg_i, rowptr, bsum, N);
    scan2<<<1, 256, 0, stream>>>(bsum, nb);
    scan3<<<blkN, 256, 0, stream>>>(rowptr, bsum, cursor, N, E);
    bscan<<<1, 256, 0, stream>>>(bhist, bcur, NB);
    bucket_fill<<<blkE, 256, 0, stream>>>(src, dst, bcur, pairs, E);
    csr_from_buckets<<<blkE, 256, 0, stream>>>(pairs, cursor, col, E);
    graph_bounds<<<1, 128, 0, stream>>>(batch, gstart, N, G);

    // ---- layer 1 (fp32 in, bf16 out) ----
    gemm128<false><<<blkGemm, 256, 0, stream>>>(x, W1, dinv, (uint2*)bufA, N);
    gather_fused<<<blkGather, 256, 0, stream>>>(bufA, rowptr, col, dinv, b1, bufB, N);

    // ---- layer 2 (bf16 in, bf16 out) ----
    gemm128<true><<<blkGemm, 256, 0, stream>>>(bufB, W2, dinv, (uint2*)bufA, N);
    gather_fused<<<blkGather, 256, 0, stream>>>(bufA, rowptr, col, dinv, b2, bufB, N);

    // ---- pool + heads ----
    hipMemsetAsync(pooled, 0, (size_t)G * HDIM * 4, stream);
    pool_partial<<<blkPool, 256, 0, stream>>>((const unsigned short*)bufB, batch, pooled, N);
    head_kernel<<<G, 64, 0, stream>>>(pooled, gstart, Wa, ba, Wv, bv, log_std, out, G);
}

// Round 6
// 445.640 us; speedup vs baseline: 7.0570x; 2.2459x over previous
//
#include <hip/hip_runtime.h>
#include <hip/hip_bf16.h>

#define FDIM 128
#define HDIM 128
#define ADIM 32
#define PCH 128      // rows per pool block
#define BSH 6        // bucket shift: 64 dst nodes per bucket
#define BWD 64
#define CHUNK 8192   // edges per binning block
#define MAXNB 2048   // max buckets supported (N <= 131072)

// bf16x2 helpers (bitwise; bf16->fp32 exact, fp32->bf16 RNE)
static __device__ __forceinline__ float bflo(unsigned int u) {
    return __builtin_bit_cast(float, u << 16);
}
static __device__ __forceinline__ float bfhi(unsigned int u) {
    return __builtin_bit_cast(float, u & 0xffff0000u);
}
static __device__ __forceinline__ unsigned int bfpack(float a, float b) {
    unsigned int ua = __builtin_bit_cast(unsigned int, a);
    unsigned int ub = __builtin_bit_cast(unsigned int, b);
    ua += 0x7fffu + ((ua >> 16) & 1u);
    ub += 0x7fffu + ((ub >> 16) & 1u);
    return (ua >> 16) | (ub & 0xffff0000u);
}

// ---------------------------------------------------------------------------
// Per-block LDS bucket histogram; dense coalesced dump (NO global atomics).
__global__ __launch_bounds__(256) void block_hist(const int* __restrict__ dst,
                                                  int* __restrict__ hist,  // [nblk][NB]
                                                  int E, int NB) {
    __shared__ int h[MAXNB];
    const int tid = threadIdx.x;
    for (int i = tid; i < NB; i += 256) h[i] = 0;
    __syncthreads();
    const int base = blockIdx.x * CHUNK;
    int lim = base + CHUNK; if (lim > E) lim = E;
    for (int i = base + tid; i < lim; i += 256) atomicAdd(&h[dst[i] >> BSH], 1);
    __syncthreads();
    int* hrow = hist + (size_t)blockIdx.x * NB;
    for (int b = tid; b < NB; b += 256) hrow[b] = h[b];
}

// Exclusive scan over M = NB*NBLK counts in bucket-major order
// (seq p -> bucket p/NBLK, block p%NBLK; gather-transposed read from hist).
__global__ void scanA(const int* __restrict__ hist, int* __restrict__ excl,
                      int* __restrict__ bsum, int M, int NB, int NBLK) {
    __shared__ int tmp[256];
    const int t = threadIdx.x;
    const int idx = blockIdx.x * 2048 + t * 8;
    int v[8], s = 0;
    #pragma unroll
    for (int i = 0; i < 8; ++i) {
        int p = idx + i;
        v[i] = (p < M) ? hist[(size_t)(p % NBLK) * NB + (p / NBLK)] : 0;
        s += v[i];
    }
    tmp[t] = s;
    __syncthreads();
    for (int off = 1; off < 256; off <<= 1) {
        int x = (t >= off) ? tmp[t - off] : 0;
        __syncthreads();
        tmp[t] += x;
        __syncthreads();
    }
    int run = tmp[t] - s;
    #pragma unroll
    for (int i = 0; i < 8; ++i) {
        int p = idx + i;
        if (p < M) excl[p] = run;
        run += v[i];
    }
    if (t == 255) bsum[blockIdx.x] = tmp[255];
}

// single-block scan of block sums (nb <= 256)
__global__ void scanB(int* __restrict__ bsum, int nb) {
    __shared__ int tmp[256];
    const int t = threadIdx.x;
    int s = (t < nb) ? bsum[t] : 0;
    tmp[t] = s;
    __syncthreads();
    for (int off = 1; off < 256; off <<= 1) {
        int x = (t >= off) ? tmp[t - off] : 0;
        __syncthreads();
        tmp[t] += x;
        __syncthreads();
    }
    if (t < nb) bsum[t] = tmp[t] - s;
}

__global__ void scanC(int* __restrict__ excl, const int* __restrict__ bsum, int M) {
    int i = blockIdx.x * 256 + threadIdx.x;
    if (i < M) excl[i] += bsum[i >> 11];
}

// Re-read edges; exact LDS cursors from scanned hist; write packed edge
// (src | node-in-bucket<<26) grouped by bucket. NO global atomics.
__global__ __launch_bounds__(256) void bucket_scatter(const int* __restrict__ src,
                                                      const int* __restrict__ dst,
                                                      const int* __restrict__ excl,
                                                      unsigned int* __restrict__ packed,
                                                      int E, int NB, int NBLK) {
    __shared__ int cur[MAXNB];
    const int tid = threadIdx.x;
    const int blk = blockIdx.x;
    for (int b = tid; b < NB; b += 256) cur[b] = excl[(size_t)b * NBLK + blk];
    __syncthreads();
    const int base = blk * CHUNK;
    int lim = base + CHUNK; if (lim > E) lim = E;
    for (int i = base + tid; i < lim; i += 256) {
        int d = dst[i];
        int s = src[i];
        int pos = atomicAdd(&cur[d >> BSH], 1);  // LDS atomic only
        packed[pos] = (unsigned)s | ((unsigned)(d & (BWD - 1)) << 26);
    }
}

// One block per bucket: in-bucket per-node counts -> rowptr + dinv + node-grouped col.
__global__ __launch_bounds__(256) void bucket_to_csr(const unsigned int* __restrict__ packed,
                                                     const int* __restrict__ excl,
                                                     int* __restrict__ rowptr,
                                                     float* __restrict__ dinv,
                                                     int* __restrict__ col,
                                                     int E, int N, int NB, int NBLK) {
    __shared__ int cnt[BWD];
    __shared__ int offs[BWD];
    const int b = blockIdx.x;
    const int tid = threadIdx.x;
    const int base = excl[(size_t)b * NBLK];
    const int next = (b + 1 < NB) ? excl[(size_t)(b + 1) * NBLK] : E;
    if (tid < BWD) cnt[tid] = 0;
    __syncthreads();
    for (int i = base + tid; i < next; i += 256) atomicAdd(&cnt[packed[i] >> 26], 1);
    __syncthreads();
    if (tid == 0) {
        int run = 0;
        for (int j = 0; j < BWD; ++j) { offs[j] = run; run += cnt[j]; }
    }
    __syncthreads();
    if (tid < BWD) {
        int node = (b << BSH) + tid;
        if (node < N) {
            rowptr[node] = base + offs[tid];
            dinv[node] = rsqrtf((float)cnt[tid] + 1.0f);
        }
        cnt[tid] = offs[tid];  // reuse as in-bucket cursors
    }
    if (b == NB - 1 && tid == 0) rowptr[N] = E;
    __syncthreads();
    for (int i = base + tid; i < next; i += 256) {
        unsigned int u = packed[i];
        int j = u >> 26;
        int pos = base + atomicAdd(&cnt[j], 1);  // LDS atomic only
        col[pos] = (int)(u & 0x03ffffffu);
    }
}

// ---------------------------------------------------------------------------
// GEMM + row-scale epilogue, bf16 output: Out[r] = bf16((X[r] @ W) * rowscale[r])
template <bool BF16IN>
__global__ __launch_bounds__(256, 2) void gemm128(const void* __restrict__ Xv,
                                                  const float* __restrict__ W,
                                                  const float* __restrict__ rowscale,
                                                  uint2* __restrict__ Out, int n) {
    __shared__ float sW[64 * 128];
    __shared__ float sX[32 * 128];
    const int tid = threadIdx.x;
    const int rbase = blockIdx.x * 32;
    int rows = n - rbase; if (rows > 32) rows = 32;

    if (BF16IN) {
        const uint2* X2 = (const uint2*)((const unsigned short*)Xv + (size_t)rbase * 128);
        float4* sX4 = (float4*)sX;
        for (int i = tid; i < rows * 32; i += 256) {
            uint2 u = X2[i];
            sX4[i] = make_float4(bflo(u.x), bfhi(u.x), bflo(u.y), bfhi(u.y));
        }
    } else {
        const float4* X4 = (const float4*)((const float*)Xv + (size_t)rbase * 128);
        float4* sX4 = (float4*)sX;
        for (int i = tid; i < rows * 32; i += 256) sX4[i] = X4[i];
    }

    const int tx = tid & 31;
    const int ty = tid >> 5;
    float acc[4][4] = {{0.f,0.f,0.f,0.f},{0.f,0.f,0.f,0.f},{0.f,0.f,0.f,0.f},{0.f,0.f,0.f,0.f}};

    for (int half = 0; half < 2; ++half) {
        __syncthreads();
        {
            const float4* W4 = (const float4*)(W + half * 64 * 128);
            float4* sW4 = (float4*)sW;
            for (int i = tid; i < 2048; i += 256) sW4[i] = W4[i];
        }
        __syncthreads();

        const float* xb = sX + ty * 4 * 128 + half * 64;
        #pragma unroll 8
        for (int kk = 0; kk < 64; ++kk) {
            const float4 w = *(const float4*)(sW + kk * 128 + tx * 4);
            float xv[4];
            #pragma unroll
            for (int i = 0; i < 4; ++i) xv[i] = xb[i * 128 + kk];
            #pragma unroll
            for (int i = 0; i < 4; ++i) {
                acc[i][0] = fmaf(xv[i], w.x, acc[i][0]);
                acc[i][1] = fmaf(xv[i], w.y, acc[i][1]);
                acc[i][2] = fmaf(xv[i], w.z, acc[i][2]);
                acc[i][3] = fmaf(xv[i], w.w, acc[i][3]);
            }
        }
    }

    #pragma unroll
    for (int i = 0; i < 4; ++i) {
        int r = rbase + ty * 4 + i;
        if (r < n) {
            float sc = rowscale[r];
            unsigned int p0 = bfpack(acc[i][0] * sc, acc[i][1] * sc);
            unsigned int p1 = bfpack(acc[i][2] * sc, acc[i][3] * sc);
            Out[(size_t)r * 32 + tx] = make_uint2(p0, p1);
        }
    }
}

// ---------------------------------------------------------------------------
// Fused CSR gather + epilogue on pre-scaled bf16 T' = (X@W)*dinv[row]:
//   h[d] = relu( (sum_{s in in(d)} T'[s] + T'[d]) * dinv[d] + bias )
// One wave per destination node, register accumulation; lane covers 2 cols.
__global__ __launch_bounds__(256) void gather_fused(const unsigned int* __restrict__ T,
                                                    const int* __restrict__ rowptr,
                                                    const int* __restrict__ col,
                                                    const float* __restrict__ dinv,
                                                    const float* __restrict__ bias,
                                                    unsigned int* __restrict__ H, int n) {
    const int d = (blockIdx.x * 256 + threadIdx.x) >> 6;
    const int lane = threadIdx.x & 63;
    if (d >= n) return;
    int e = rowptr[d];
    const int end = rowptr[d + 1];

    float ax = 0.f, ay = 0.f, bx = 0.f, by = 0.f;
    for (; e + 3 < end; e += 4) {
        int s0 = col[e], s1 = col[e + 1], s2 = col[e + 2], s3 = col[e + 3];
        unsigned int u0 = T[(size_t)s0 * 64 + lane];
        unsigned int u1 = T[(size_t)s1 * 64 + lane];
        unsigned int u2 = T[(size_t)s2 * 64 + lane];
        unsigned int u3 = T[(size_t)s3 * 64 + lane];
        ax += bflo(u0) + bflo(u1); ay += bfhi(u0) + bfhi(u1);
        bx += bflo(u2) + bflo(u3); by += bfhi(u2) + bfhi(u3);
    }
    for (; e < end; ++e) {
        unsigned int u = T[(size_t)col[e] * 64 + lane];
        ax += bflo(u); ay += bfhi(u);
    }

    unsigned int su = T[(size_t)d * 64 + lane];
    const float di = dinv[d];
    const float2 bv = ((const float2*)bias)[lane];
    float ox = fmaxf(fmaf(ax + bx + bflo(su), di, bv.x), 0.f);
    float oy = fmaxf(fmaf(ay + by + bfhi(su), di, bv.y), 0.f);
    H[(size_t)d * 64 + lane] = bfpack(ox, oy);
}

// ---------------------------------------------------------------------------
__global__ void graph_bounds(const int* __restrict__ batch, int* __restrict__ gstart,
                             int n, int G) {
    int g = blockIdx.x * 128 + threadIdx.x;
    if (g > G) return;
    int lo = 0, hi = n;
    while (lo < hi) { int mid = (lo + hi) >> 1; if (batch[mid] < g) lo = mid + 1; else hi = mid; }
    gstart[g] = lo;
}

// Parallel partial-sum pool over bf16 h (batch sorted -> per-thread running acc)
__global__ __launch_bounds__(256) void pool_partial(const unsigned short* __restrict__ h,
                                                    const int* __restrict__ batch,
                                                    float* __restrict__ pooled, int n) {
    const int c = threadIdx.x & 127;
    const int half = threadIdx.x >> 7;
    int r = blockIdx.x * PCH + half;
    int rend = blockIdx.x * PCH + PCH;
    if (rend > n) rend = n;
    float acc = 0.f;
    int cur = -1;
    for (; r < rend; r += 2) {
        int g = batch[r];
        if (g != cur) {
            if (cur >= 0) atomicAdd(&pooled[(size_t)cur * 128 + c], acc);
            acc = 0.f;
            cur = g;
        }
        acc += __builtin_bit_cast(float, (unsigned int)h[(size_t)r * 128 + c] << 16);
    }
    if (cur >= 0) atomicAdd(&pooled[(size_t)cur * 128 + c], acc);
}

// ---------------------------------------------------------------------------
// out layout: [G*A action_mean][A std][G value]
__global__ void head_kernel(const float* __restrict__ pooled, const int* __restrict__ gstart,
                            const float* __restrict__ Wa, const float* __restrict__ ba,
                            const float* __restrict__ Wv, const float* __restrict__ bv,
                            const float* __restrict__ log_std, float* __restrict__ out, int G) {
    int g = blockIdx.x;
    int t = threadIdx.x;  // 64
    __shared__ float sp[128];
    float inv = 1.0f / fmaxf((float)(gstart[g + 1] - gstart[g]), 1.0f);
    sp[t] = pooled[(size_t)g * 128 + t] * inv;
    sp[t + 64] = pooled[(size_t)g * 128 + 64 + t] * inv;
    __syncthreads();
    if (t < 32) {
        float s = 0.f;
        #pragma unroll 8
        for (int k = 0; k < 128; ++k) s = fmaf(sp[k], Wa[k * ADIM + t], s);
        out[g * ADIM + t] = s + ba[t];
        if (g == 0) out[G * ADIM + t] = expf(log_std[t]);
    } else if (t == 32) {
        float s = 0.f;
        #pragma unroll 8
        for (int k = 0; k < 128; ++k) s = fmaf(sp[k], Wv[k], s);
        out[G * ADIM + ADIM + g] = s + bv[0];
    }
}

// ---------------------------------------------------------------------------
extern "C" void kernel_launch(void* const* d_in, const int* in_sizes, int n_in,
                              void* d_out, int out_size, void* d_ws, size_t ws_size,
                              hipStream_t stream) {
    const float* x       = (const float*)d_in[0];
    const int*   ei      = (const int*)d_in[1];
    const int*   batch   = (const int*)d_in[2];
    const float* W1      = (const float*)d_in[3];
    const float* b1      = (const float*)d_in[4];
    const float* W2      = (const float*)d_in[5];
    const float* b2      = (const float*)d_in[6];
    const float* Wa      = (const float*)d_in[7];
    const float* ba      = (const float*)d_in[8];
    const float* Wv      = (const float*)d_in[9];
    const float* bv      = (const float*)d_in[10];
    const float* log_std = (const float*)d_in[11];
    float* out = (float*)d_out;

    const int N = in_sizes[0] / FDIM;
    const int E = in_sizes[1] / 2;
    const int G = (out_size - ADIM) / (ADIM + 1);
    const int NB = (N + BWD - 1) >> BSH;          // buckets (<= MAXNB for N <= 131072)
    const int NBLK = (E + CHUNK - 1) / CHUNK;     // binning blocks
    const int M = NB * NBLK;                      // scan length
    const int nscanA = (M + 2047) / 2048;         // <= 256

    const int* src = ei;
    const int* dst = ei + E;

    auto align = [](size_t v) { return (v + 255) & ~(size_t)255; };
    char* ws = (char*)d_ws;
    size_t off = 0;
    int*   hist   = (int*)(ws + off);   off = align(off + (size_t)M * 4);
    int*   excl   = (int*)(ws + off);   off = align(off + (size_t)M * 4);
    int*   bsum   = (int*)(ws + off);   off = align(off + (size_t)256 * 4);
    int*   rowptr = (int*)(ws + off);   off = align(off + (size_t)(N + 1) * 4);
    int*   gstart = (int*)(ws + off);   off = align(off + (size_t)(G + 1) * 4);
    float* dinv   = (float*)(ws + off); off = align(off + (size_t)N * 4);
    float* pooled = (float*)(ws + off); off = align(off + (size_t)G * HDIM * 4);
    unsigned int* packed = (unsigned int*)(ws + off); off = align(off + (size_t)E * 4);
    int*   col    = (int*)(ws + off);   off = align(off + (size_t)E * 4);
    unsigned int* bufA = (unsigned int*)(ws + off); off = align(off + (size_t)N * 64 * 4);
    unsigned int* bufB = (unsigned int*)(ws + off); off = align(off + (size_t)N * 64 * 4);
    (void)ws_size;

    const int blkGemm = (N + 31) / 32;
    const int blkGather = (int)(((long long)N * 64 + 255) / 256);
    const int blkPool = (N + PCH - 1) / PCH;

    // ---- binning -> CSR + dinv (no global atomics) ----
    block_hist<<<NBLK, 256, 0, stream>>>(dst, hist, E, NB);
    scanA<<<nscanA, 256, 0, stream>>>(hist, excl, bsum, M, NB, NBLK);
    scanB<<<1, 256, 0, stream>>>(bsum, nscanA);
    scanC<<<(M + 255) / 256, 256, 0, stream>>>(excl, bsum, M);
    bucket_scatter<<<NBLK, 256, 0, stream>>>(src, dst, excl, packed, E, NB, NBLK);
    bucket_to_csr<<<NB, 256, 0, stream>>>(packed, excl, rowptr, dinv, col, E, N, NB, NBLK);
    graph_bounds<<<1, 128, 0, stream>>>(batch, gstart, N, G);

    // ---- layer 1 (fp32 in, bf16 out) ----
    gemm128<false><<<blkGemm, 256, 0, stream>>>(x, W1, dinv, (uint2*)bufA, N);
    gather_fused<<<blkGather, 256, 0, stream>>>(bufA, rowptr, col, dinv, b1, bufB, N);

    // ---- layer 2 (bf16 in, bf16 out) ----
    gemm128<true><<<blkGemm, 256, 0, stream>>>(bufB, W2, dinv, (uint2*)bufA, N);
    gather_fused<<<blkGather, 256, 0, stream>>>(bufA, rowptr, col, dinv, b2, bufB, N);

    // ---- pool + heads ----
    hipMemsetAsync(pooled, 0, (size_t)G * HDIM * 4, stream);
    pool_partial<<<blkPool, 256, 0, stream>>>((const unsigned short*)bufB, batch, pooled, N);
    head_kernel<<<G, 64, 0, stream>>>(pooled, gstart, Wa, ba, Wv, bv, log_std, out, G);
}

// Round 7
// 414.390 us; speedup vs baseline: 7.5892x; 1.0754x over previous
//
#include <hip/hip_runtime.h>
#include <hip/hip_bf16.h>

#define FDIM 128
#define HDIM 128
#define ADIM 32
#define PCH 128      // rows per pool block
#define BSH 6        // bucket shift: 64 dst nodes per bucket
#define BWD 64
#define CHUNK 8192   // edges per binning block
#define MAXNB 2048   // max buckets supported (N <= 131072)

// bf16x2 helpers (bitwise; bf16->fp32 exact, fp32->bf16 RNE)
static __device__ __forceinline__ float bflo(unsigned int u) {
    return __builtin_bit_cast(float, u << 16);
}
static __device__ __forceinline__ float bfhi(unsigned int u) {
    return __builtin_bit_cast(float, u & 0xffff0000u);
}
static __device__ __forceinline__ unsigned int bfpack(float a, float b) {
    unsigned int ua = __builtin_bit_cast(unsigned int, a);
    unsigned int ub = __builtin_bit_cast(unsigned int, b);
    ua += 0x7fffu + ((ua >> 16) & 1u);
    ub += 0x7fffu + ((ub >> 16) & 1u);
    return (ua >> 16) | (ub & 0xffff0000u);
}

// ---------------------------------------------------------------------------
// fp8 e4m3 (OCP) x4 <-> fp32 helpers. HW path: gfx940+ cvt instructions.
#if defined(__has_builtin) && __has_builtin(__builtin_amdgcn_cvt_pk_f32_fp8) && \
    __has_builtin(__builtin_amdgcn_cvt_pk_fp8_f32)
#define FP8_HW 1
#endif

typedef float v2f __attribute__((ext_vector_type(2)));

static __device__ __forceinline__ float4 fp8x4_dec(unsigned int u) {
#ifdef FP8_HW
    v2f lo = __builtin_amdgcn_cvt_pk_f32_fp8(u, false);
    v2f hi = __builtin_amdgcn_cvt_pk_f32_fp8(u, true);
    return make_float4(lo.x, lo.y, hi.x, hi.y);
#else
    float r[4];
    #pragma unroll
    for (int i = 0; i < 4; ++i) {
        unsigned b = (u >> (8 * i)) & 0xffu;
        unsigned s = b >> 7, e = (b >> 3) & 0xfu, m = b & 7u;
        float v = (e == 0) ? (float)m * 0.001953125f
                           : __builtin_bit_cast(float, ((e + 120u) << 23) | (m << 20));
        r[i] = s ? -v : v;
    }
    return make_float4(r[0], r[1], r[2], r[3]);
#endif
}

#ifndef FP8_HW
static __device__ __forceinline__ unsigned int fp8_enc1(float x) {
    unsigned s = __builtin_bit_cast(unsigned, x) >> 31;
    float ax = fabsf(x);
    if (ax > 448.f) return (s << 7) | 0x7Eu;          // clamp to max finite
    if (ax < 0.0009765625f) return s << 7;            // -> 0
    int e2 = (int)((__builtin_bit_cast(unsigned, ax) >> 23) & 0xff) - 127;
    int qe = (e2 < -6 ? -6 : e2) - 3;                 // quantum exponent
    float q = __builtin_bit_cast(float, (unsigned)((qe + 127) << 23));
    float r = rintf(ax / q) * q;                      // RNE
    if (r > 448.f) return (s << 7) | 0x7Eu;
    if (r < 0.001953125f) return s << 7;
    unsigned ub = __builtin_bit_cast(unsigned, r);
    int re = (int)((ub >> 23) & 0xff) - 127;
    if (re < -6) {                                    // denormal
        unsigned m = (unsigned)rintf(r * 512.f);
        return (s << 7) | m;
    }
    return (s << 7) | ((unsigned)(re + 7) << 3) | ((ub >> 20) & 7u);
}
#endif

static __device__ __forceinline__ unsigned int fp8x4_enc(float a, float b, float c, float d) {
#ifdef FP8_HW
    int p = __builtin_amdgcn_cvt_pk_fp8_f32(a, b, 0, false);
    p = __builtin_amdgcn_cvt_pk_fp8_f32(c, d, p, true);
    return (unsigned int)p;
#else
    return fp8_enc1(a) | (fp8_enc1(b) << 8) | (fp8_enc1(c) << 16) | (fp8_enc1(d) << 24);
#endif
}

// ---------------------------------------------------------------------------
// Per-block LDS bucket histogram; dense coalesced dump (NO global atomics).
__global__ __launch_bounds__(256) void block_hist(const int* __restrict__ dst,
                                                  int* __restrict__ hist,  // [nblk][NB]
                                                  int E, int NB) {
    __shared__ int h[MAXNB];
    const int tid = threadIdx.x;
    for (int i = tid; i < NB; i += 256) h[i] = 0;
    __syncthreads();
    const int base = blockIdx.x * CHUNK;
    int lim = base + CHUNK; if (lim > E) lim = E;
    for (int i = base + tid; i < lim; i += 256) atomicAdd(&h[dst[i] >> BSH], 1);
    __syncthreads();
    int* hrow = hist + (size_t)blockIdx.x * NB;
    for (int b = tid; b < NB; b += 256) hrow[b] = h[b];
}

// Exclusive scan over M = NB*NBLK counts in bucket-major order.
__global__ void scanA(const int* __restrict__ hist, int* __restrict__ excl,
                      int* __restrict__ bsum, int M, int NB, int NBLK) {
    __shared__ int tmp[256];
    const int t = threadIdx.x;
    const int idx = blockIdx.x * 2048 + t * 8;
    int v[8], s = 0;
    #pragma unroll
    for (int i = 0; i < 8; ++i) {
        int p = idx + i;
        v[i] = (p < M) ? hist[(size_t)(p % NBLK) * NB + (p / NBLK)] : 0;
        s += v[i];
    }
    tmp[t] = s;
    __syncthreads();
    for (int off = 1; off < 256; off <<= 1) {
        int x = (t >= off) ? tmp[t - off] : 0;
        __syncthreads();
        tmp[t] += x;
        __syncthreads();
    }
    int run = tmp[t] - s;
    #pragma unroll
    for (int i = 0; i < 8; ++i) {
        int p = idx + i;
        if (p < M) excl[p] = run;
        run += v[i];
    }
    if (t == 255) bsum[blockIdx.x] = tmp[255];
}

__global__ void scanB(int* __restrict__ bsum, int nb) {
    __shared__ int tmp[256];
    const int t = threadIdx.x;
    int s = (t < nb) ? bsum[t] : 0;
    tmp[t] = s;
    __syncthreads();
    for (int off = 1; off < 256; off <<= 1) {
        int x = (t >= off) ? tmp[t - off] : 0;
        __syncthreads();
        tmp[t] += x;
        __syncthreads();
    }
    if (t < nb) bsum[t] = tmp[t] - s;
}

__global__ void scanC(int* __restrict__ excl, const int* __restrict__ bsum, int M) {
    int i = blockIdx.x * 256 + threadIdx.x;
    if (i < M) excl[i] += bsum[i >> 11];
}

// Re-read edges; exact LDS cursors from scanned hist; write packed edge
// (src | node-in-bucket<<26) grouped by bucket. NO global atomics.
__global__ __launch_bounds__(256) void bucket_scatter(const int* __restrict__ src,
                                                      const int* __restrict__ dst,
                                                      const int* __restrict__ excl,
                                                      unsigned int* __restrict__ packed,
                                                      int E, int NB, int NBLK) {
    __shared__ int cur[MAXNB];
    const int tid = threadIdx.x;
    const int blk = blockIdx.x;
    for (int b = tid; b < NB; b += 256) cur[b] = excl[(size_t)b * NBLK + blk];
    __syncthreads();
    const int base = blk * CHUNK;
    int lim = base + CHUNK; if (lim > E) lim = E;
    for (int i = base + tid; i < lim; i += 256) {
        int d = dst[i];
        int s = src[i];
        int pos = atomicAdd(&cur[d >> BSH], 1);  // LDS atomic only
        packed[pos] = (unsigned)s | ((unsigned)(d & (BWD - 1)) << 26);
    }
}

// One block per bucket: in-bucket per-node counts -> rowptr + dinv + node-grouped col.
__global__ __launch_bounds__(256) void bucket_to_csr(const unsigned int* __restrict__ packed,
                                                     const int* __restrict__ excl,
                                                     int* __restrict__ rowptr,
                                                     float* __restrict__ dinv,
                                                     int* __restrict__ col,
                                                     int E, int N, int NB, int NBLK) {
    __shared__ int cnt[BWD];
    __shared__ int offs[BWD];
    const int b = blockIdx.x;
    const int tid = threadIdx.x;
    const int base = excl[(size_t)b * NBLK];
    const int next = (b + 1 < NB) ? excl[(size_t)(b + 1) * NBLK] : E;
    if (tid < BWD) cnt[tid] = 0;
    __syncthreads();
    for (int i = base + tid; i < next; i += 256) atomicAdd(&cnt[packed[i] >> 26], 1);
    __syncthreads();
    if (tid == 0) {
        int run = 0;
        for (int j = 0; j < BWD; ++j) { offs[j] = run; run += cnt[j]; }
    }
    __syncthreads();
    if (tid < BWD) {
        int node = (b << BSH) + tid;
        if (node < N) {
            rowptr[node] = base + offs[tid];
            dinv[node] = rsqrtf((float)cnt[tid] + 1.0f);
        }
        cnt[tid] = offs[tid];  // reuse as in-bucket cursors
    }
    if (b == NB - 1 && tid == 0) rowptr[N] = E;
    __syncthreads();
    for (int i = base + tid; i < next; i += 256) {
        unsigned int u = packed[i];
        int j = u >> 26;
        int pos = base + atomicAdd(&cnt[j], 1);  // LDS atomic only
        col[pos] = (int)(u & 0x03ffffffu);
    }
}

// ---------------------------------------------------------------------------
// GEMM + row-scale epilogue, fp8 output: Out[r] = fp8((X[r] @ W) * rowscale[r])
template <bool BF16IN>
__global__ __launch_bounds__(256, 2) void gemm128(const void* __restrict__ Xv,
                                                  const float* __restrict__ W,
                                                  const float* __restrict__ rowscale,
                                                  unsigned int* __restrict__ Out, int n) {
    __shared__ float sW[64 * 128];
    __shared__ float sX[32 * 128];
    const int tid = threadIdx.x;
    const int rbase = blockIdx.x * 32;
    int rows = n - rbase; if (rows > 32) rows = 32;

    if (BF16IN) {
        const uint2* X2 = (const uint2*)((const unsigned short*)Xv + (size_t)rbase * 128);
        float4* sX4 = (float4*)sX;
        for (int i = tid; i < rows * 32; i += 256) {
            uint2 u = X2[i];
            sX4[i] = make_float4(bflo(u.x), bfhi(u.x), bflo(u.y), bfhi(u.y));
        }
    } else {
        const float4* X4 = (const float4*)((const float*)Xv + (size_t)rbase * 128);
        float4* sX4 = (float4*)sX;
        for (int i = tid; i < rows * 32; i += 256) sX4[i] = X4[i];
    }

    const int tx = tid & 31;
    const int ty = tid >> 5;
    float acc[4][4] = {{0.f,0.f,0.f,0.f},{0.f,0.f,0.f,0.f},{0.f,0.f,0.f,0.f},{0.f,0.f,0.f,0.f}};

    for (int half = 0; half < 2; ++half) {
        __syncthreads();
        {
            const float4* W4 = (const float4*)(W + half * 64 * 128);
            float4* sW4 = (float4*)sW;
            for (int i = tid; i < 2048; i += 256) sW4[i] = W4[i];
        }
        __syncthreads();

        const float* xb = sX + ty * 4 * 128 + half * 64;
        #pragma unroll 8
        for (int kk = 0; kk < 64; ++kk) {
            const float4 w = *(const float4*)(sW + kk * 128 + tx * 4);
            float xv[4];
            #pragma unroll
            for (int i = 0; i < 4; ++i) xv[i] = xb[i * 128 + kk];
            #pragma unroll
            for (int i = 0; i < 4; ++i) {
                acc[i][0] = fmaf(xv[i], w.x, acc[i][0]);
                acc[i][1] = fmaf(xv[i], w.y, acc[i][1]);
                acc[i][2] = fmaf(xv[i], w.z, acc[i][2]);
                acc[i][3] = fmaf(xv[i], w.w, acc[i][3]);
            }
        }
    }

    #pragma unroll
    for (int i = 0; i < 4; ++i) {
        int r = rbase + ty * 4 + i;
        if (r < n) {
            float sc = rowscale[r];
            Out[(size_t)r * 32 + tx] =
                fp8x4_enc(acc[i][0] * sc, acc[i][1] * sc, acc[i][2] * sc, acc[i][3] * sc);
        }
    }
}

// ---------------------------------------------------------------------------
// Fused CSR gather + epilogue on pre-scaled fp8 T' = (X@W)*dinv[row]:
//   h[d] = relu( (sum_{s in in(d)} T'[s] + T'[d]) * dinv[d] + bias )
// One wave per dst node; each HALF-wave processes its own edge (row = 128 B);
// lane covers 4 cols; cross-half combine via shfl_xor(32). Output bf16.
__global__ __launch_bounds__(256) void gather_fused(const unsigned int* __restrict__ T8,
                                                    const int* __restrict__ rowptr,
                                                    const int* __restrict__ col,
                                                    const float* __restrict__ dinv,
                                                    const float* __restrict__ bias,
                                                    unsigned int* __restrict__ H, int n) {
    const int d = (blockIdx.x * 256 + threadIdx.x) >> 6;
    const int lane = threadIdx.x & 63;
    if (d >= n) return;
    const int half = lane >> 5, sl = lane & 31;
    const int start = rowptr[d], end = rowptr[d + 1];

    float a0 = 0.f, a1 = 0.f, a2 = 0.f, a3 = 0.f;
    int e = start + half;
    for (; e + 2 < end; e += 4) {  // this half handles e and e+2
        unsigned int u0 = T8[(size_t)col[e] * 32 + sl];
        unsigned int u1 = T8[(size_t)col[e + 2] * 32 + sl];
        float4 f0 = fp8x4_dec(u0);
        float4 f1 = fp8x4_dec(u1);
        a0 += f0.x + f1.x; a1 += f0.y + f1.y;
        a2 += f0.z + f1.z; a3 += f0.w + f1.w;
    }
    if (e < end) {
        float4 f = fp8x4_dec(T8[(size_t)col[e] * 32 + sl]);
        a0 += f.x; a1 += f.y; a2 += f.z; a3 += f.w;
    }
    // combine the two half-wave partial sums (lane l <-> l^32 hold same cols)
    a0 += __shfl_xor(a0, 32);
    a1 += __shfl_xor(a1, 32);
    a2 += __shfl_xor(a2, 32);
    a3 += __shfl_xor(a3, 32);

    float4 sf = fp8x4_dec(T8[(size_t)d * 32 + sl]);
    const float di = dinv[d];
    const float2 bv = ((const float2*)bias)[2 * sl + half];
    float c0, c1;
    if (half == 0) { c0 = a0 + sf.x; c1 = a1 + sf.y; }
    else           { c0 = a2 + sf.z; c1 = a3 + sf.w; }
    float o0 = fmaxf(fmaf(c0, di, bv.x), 0.f);
    float o1 = fmaxf(fmaf(c1, di, bv.y), 0.f);
    H[(size_t)d * 64 + 2 * sl + half] = bfpack(o0, o1);
}

// ---------------------------------------------------------------------------
__global__ void graph_bounds(const int* __restrict__ batch, int* __restrict__ gstart,
                             int n, int G) {
    int g = blockIdx.x * 128 + threadIdx.x;
    if (g > G) return;
    int lo = 0, hi = n;
    while (lo < hi) { int mid = (lo + hi) >> 1; if (batch[mid] < g) lo = mid + 1; else hi = mid; }
    gstart[g] = lo;
}

// Parallel partial-sum pool over bf16 h (batch sorted -> per-thread running acc)
__global__ __launch_bounds__(256) void pool_partial(const unsigned short* __restrict__ h,
                                                    const int* __restrict__ batch,
                                                    float* __restrict__ pooled, int n) {
    const int c = threadIdx.x & 127;
    const int half = threadIdx.x >> 7;
    int r = blockIdx.x * PCH + half;
    int rend = blockIdx.x * PCH + PCH;
    if (rend > n) rend = n;
    float acc = 0.f;
    int cur = -1;
    for (; r < rend; r += 2) {
        int g = batch[r];
        if (g != cur) {
            if (cur >= 0) atomicAdd(&pooled[(size_t)cur * 128 + c], acc);
            acc = 0.f;
            cur = g;
        }
        acc += __builtin_bit_cast(float, (unsigned int)h[(size_t)r * 128 + c] << 16);
    }
    if (cur >= 0) atomicAdd(&pooled[(size_t)cur * 128 + c], acc);
}

// ---------------------------------------------------------------------------
// out layout: [G*A action_mean][A std][G value]
__global__ void head_kernel(const float* __restrict__ pooled, const int* __restrict__ gstart,
                            const float* __restrict__ Wa, const float* __restrict__ ba,
                            const float* __restrict__ Wv, const float* __restrict__ bv,
                            const float* __restrict__ log_std, float* __restrict__ out, int G) {
    int g = blockIdx.x;
    int t = threadIdx.x;  // 64
    __shared__ float sp[128];
    float inv = 1.0f / fmaxf((float)(gstart[g + 1] - gstart[g]), 1.0f);
    sp[t] = pooled[(size_t)g * 128 + t] * inv;
    sp[t + 64] = pooled[(size_t)g * 128 + 64 + t] * inv;
    __syncthreads();
    if (t < 32) {
        float s = 0.f;
        #pragma unroll 8
        for (int k = 0; k < 128; ++k) s = fmaf(sp[k], Wa[k * ADIM + t], s);
        out[g * ADIM + t] = s + ba[t];
        if (g == 0) out[G * ADIM + t] = expf(log_std[t]);
    } else if (t == 32) {
        float s = 0.f;
        #pragma unroll 8
        for (int k = 0; k < 128; ++k) s = fmaf(sp[k], Wv[k], s);
        out[G * ADIM + ADIM + g] = s + bv[0];
    }
}

// ---------------------------------------------------------------------------
extern "C" void kernel_launch(void* const* d_in, const int* in_sizes, int n_in,
                              void* d_out, int out_size, void* d_ws, size_t ws_size,
                              hipStream_t stream) {
    const float* x       = (const float*)d_in[0];
    const int*   ei      = (const int*)d_in[1];
    const int*   batch   = (const int*)d_in[2];
    const float* W1      = (const float*)d_in[3];
    const float* b1      = (const float*)d_in[4];
    const float* W2      = (const float*)d_in[5];
    const float* b2      = (const float*)d_in[6];
    const float* Wa      = (const float*)d_in[7];
    const float* ba      = (const float*)d_in[8];
    const float* Wv      = (const float*)d_in[9];
    const float* bv      = (const float*)d_in[10];
    const float* log_std = (const float*)d_in[11];
    float* out = (float*)d_out;

    const int N = in_sizes[0] / FDIM;
    const int E = in_sizes[1] / 2;
    const int G = (out_size - ADIM) / (ADIM + 1);
    const int NB = (N + BWD - 1) >> BSH;          // buckets (<= MAXNB for N <= 131072)
    const int NBLK = (E + CHUNK - 1) / CHUNK;     // binning blocks
    const int M = NB * NBLK;                      // scan length
    const int nscanA = (M + 2047) / 2048;         // <= 256

    const int* src = ei;
    const int* dst = ei + E;

    auto align = [](size_t v) { return (v + 255) & ~(size_t)255; };
    char* ws = (char*)d_ws;
    size_t off = 0;
    int*   hist   = (int*)(ws + off);   off = align(off + (size_t)M * 4);
    int*   excl   = (int*)(ws + off);   off = align(off + (size_t)M * 4);
    int*   bsum   = (int*)(ws + off);   off = align(off + (size_t)256 * 4);
    int*   rowptr = (int*)(ws + off);   off = align(off + (size_t)(N + 1) * 4);
    int*   gstart = (int*)(ws + off);   off = align(off + (size_t)(G + 1) * 4);
    float* dinv   = (float*)(ws + off); off = align(off + (size_t)N * 4);
    float* pooled = (float*)(ws + off); off = align(off + (size_t)G * HDIM * 4);
    unsigned int* packed = (unsigned int*)(ws + off); off = align(off + (size_t)E * 4);
    int*   col    = (int*)(ws + off);   off = align(off + (size_t)E * 4);
    unsigned int* bufA = (unsigned int*)(ws + off); off = align(off + (size_t)N * 32 * 4);  // fp8 N x 128
    unsigned int* bufB = (unsigned int*)(ws + off); off = align(off + (size_t)N * 64 * 4);  // bf16 N x 128
    (void)ws_size;

    const int blkGemm = (N + 31) / 32;
    const int blkGather = (int)(((long long)N * 64 + 255) / 256);
    const int blkPool = (N + PCH - 1) / PCH;

    // ---- binning -> CSR + dinv (no global atomics) ----
    block_hist<<<NBLK, 256, 0, stream>>>(dst, hist, E, NB);
    scanA<<<nscanA, 256, 0, stream>>>(hist, excl, bsum, M, NB, NBLK);
    scanB<<<1, 256, 0, stream>>>(bsum, nscanA);
    scanC<<<(M + 255) / 256, 256, 0, stream>>>(excl, bsum, M);
    bucket_scatter<<<NBLK, 256, 0, stream>>>(src, dst, excl, packed, E, NB, NBLK);
    bucket_to_csr<<<NB, 256, 0, stream>>>(packed, excl, rowptr, dinv, col, E, N, NB, NBLK);
    graph_bounds<<<1, 128, 0, stream>>>(batch, gstart, N, G);

    // ---- layer 1 (fp32 in, fp8 out) ----
    gemm128<false><<<blkGemm, 256, 0, stream>>>(x, W1, dinv, bufA, N);
    gather_fused<<<blkGather, 256, 0, stream>>>(bufA, rowptr, col, dinv, b1, bufB, N);

    // ---- layer 2 (bf16 in, fp8 out) ----
    gemm128<true><<<blkGemm, 256, 0, stream>>>(bufB, W2, dinv, bufA, N);
    gather_fused<<<blkGather, 256, 0, stream>>>(bufA, rowptr, col, dinv, b2, bufB, N);

    // ---- pool + heads ----
    hipMemsetAsync(pooled, 0, (size_t)G * HDIM * 4, stream);
    pool_partial<<<blkPool, 256, 0, stream>>>((const unsigned short*)bufB, batch, pooled, N);
    head_kernel<<<G, 64, 0, stream>>>(pooled, gstart, Wa, ba, Wv, bv, log_std, out, G);
}

// Round 8
// 363.037 us; speedup vs baseline: 8.6627x; 1.1415x over previous
//
#include <hip/hip_runtime.h>
#include <hip/hip_bf16.h>

#define FDIM 128
#define HDIM 128
#define ADIM 32
#define PCH 128      // rows per pool block
#define BSH 6        // bucket shift: 64 dst nodes per bucket
#define BWD 64
#define CHUNK 8192   // edges per binning block
#define MAXNB 2048   // max buckets supported (N <= 131072)

typedef short v8s __attribute__((ext_vector_type(8)));
typedef float v4f __attribute__((ext_vector_type(4)));
typedef float v2f __attribute__((ext_vector_type(2)));

// bf16x2 helpers (bitwise; bf16->fp32 exact, fp32->bf16 RNE)
static __device__ __forceinline__ float bflo(unsigned int u) {
    return __builtin_bit_cast(float, u << 16);
}
static __device__ __forceinline__ float bfhi(unsigned int u) {
    return __builtin_bit_cast(float, u & 0xffff0000u);
}
static __device__ __forceinline__ unsigned int bfpack(float a, float b) {
    unsigned int ua = __builtin_bit_cast(unsigned int, a);
    unsigned int ub = __builtin_bit_cast(unsigned int, b);
    ua += 0x7fffu + ((ua >> 16) & 1u);
    ub += 0x7fffu + ((ub >> 16) & 1u);
    return (ua >> 16) | (ub & 0xffff0000u);
}

// ---------------------------------------------------------------------------
// fp8 e4m3 (OCP) helpers. HW path: gfx950 cvt instructions.
#if defined(__has_builtin) && __has_builtin(__builtin_amdgcn_cvt_pk_f32_fp8) && \
    __has_builtin(__builtin_amdgcn_cvt_pk_fp8_f32)
#define FP8_HW 1
#endif

static __device__ __forceinline__ float4 fp8x4_dec(unsigned int u) {
#ifdef FP8_HW
    v2f lo = __builtin_amdgcn_cvt_pk_f32_fp8(u, false);
    v2f hi = __builtin_amdgcn_cvt_pk_f32_fp8(u, true);
    return make_float4(lo.x, lo.y, hi.x, hi.y);
#else
    float r[4];
    #pragma unroll
    for (int i = 0; i < 4; ++i) {
        unsigned b = (u >> (8 * i)) & 0xffu;
        unsigned s = b >> 7, e = (b >> 3) & 0xfu, m = b & 7u;
        float v = (e == 0) ? (float)m * 0.001953125f
                           : __builtin_bit_cast(float, ((e + 120u) << 23) | (m << 20));
        r[i] = s ? -v : v;
    }
    return make_float4(r[0], r[1], r[2], r[3]);
#endif
}

#ifndef FP8_HW
static __device__ __forceinline__ unsigned int fp8_enc1(float x) {
    unsigned s = __builtin_bit_cast(unsigned, x) >> 31;
    float ax = fabsf(x);
    if (ax > 448.f) return (s << 7) | 0x7Eu;
    if (ax < 0.0009765625f) return s << 7;
    int e2 = (int)((__builtin_bit_cast(unsigned, ax) >> 23) & 0xff) - 127;
    int qe = (e2 < -6 ? -6 : e2) - 3;
    float q = __builtin_bit_cast(float, (unsigned)((qe + 127) << 23));
    float r = rintf(ax / q) * q;
    if (r > 448.f) return (s << 7) | 0x7Eu;
    if (r < 0.001953125f) return s << 7;
    unsigned ub = __builtin_bit_cast(unsigned, r);
    int re = (int)((ub >> 23) & 0xff) - 127;
    if (re < -6) {
        unsigned m = (unsigned)rintf(r * 512.f);
        return (s << 7) | m;
    }
    return (s << 7) | ((unsigned)(re + 7) << 3) | ((ub >> 20) & 7u);
}
#endif

static __device__ __forceinline__ unsigned char fp8_enc_byte(float v) {
#ifdef FP8_HW
    return (unsigned char)(__builtin_amdgcn_cvt_pk_fp8_f32(v, v, 0, false) & 0xff);
#else
    return (unsigned char)fp8_enc1(v);
#endif
}

// ---------------------------------------------------------------------------
// Per-block LDS bucket histogram; dense coalesced dump (NO global atomics).
__global__ __launch_bounds__(256) void block_hist(const int* __restrict__ dst,
                                                  int* __restrict__ hist,  // [nblk][NB]
                                                  int E, int NB) {
    __shared__ int h[MAXNB];
    const int tid = threadIdx.x;
    for (int i = tid; i < NB; i += 256) h[i] = 0;
    __syncthreads();
    const int base = blockIdx.x * CHUNK;
    int lim = base + CHUNK; if (lim > E) lim = E;
    for (int i = base + tid; i < lim; i += 256) atomicAdd(&h[dst[i] >> BSH], 1);
    __syncthreads();
    int* hrow = hist + (size_t)blockIdx.x * NB;
    for (int b = tid; b < NB; b += 256) hrow[b] = h[b];
}

// Exclusive scan over M = NB*NBLK counts in bucket-major order.
__global__ void scanA(const int* __restrict__ hist, int* __restrict__ excl,
                      int* __restrict__ bsum, int M, int NB, int NBLK) {
    __shared__ int tmp[256];
    const int t = threadIdx.x;
    const int idx = blockIdx.x * 2048 + t * 8;
    int v[8], s = 0;
    #pragma unroll
    for (int i = 0; i < 8; ++i) {
        int p = idx + i;
        v[i] = (p < M) ? hist[(size_t)(p % NBLK) * NB + (p / NBLK)] : 0;
        s += v[i];
    }
    tmp[t] = s;
    __syncthreads();
    for (int off = 1; off < 256; off <<= 1) {
        int x = (t >= off) ? tmp[t - off] : 0;
        __syncthreads();
        tmp[t] += x;
        __syncthreads();
    }
    int run = tmp[t] - s;
    #pragma unroll
    for (int i = 0; i < 8; ++i) {
        int p = idx + i;
        if (p < M) excl[p] = run;
        run += v[i];
    }
    if (t == 255) bsum[blockIdx.x] = tmp[255];
}

__global__ void scanB(int* __restrict__ bsum, int nb) {
    __shared__ int tmp[256];
    const int t = threadIdx.x;
    int s = (t < nb) ? bsum[t] : 0;
    tmp[t] = s;
    __syncthreads();
    for (int off = 1; off < 256; off <<= 1) {
        int x = (t >= off) ? tmp[t - off] : 0;
        __syncthreads();
        tmp[t] += x;
        __syncthreads();
    }
    if (t < nb) bsum[t] = tmp[t] - s;
}

// Re-read edges; exact LDS cursors from scanned hist (+bsum fixup folded in);
// write packed edge (src | node-in-bucket<<26) grouped by bucket.
__global__ __launch_bounds__(256) void bucket_scatter(const int* __restrict__ src,
                                                      const int* __restrict__ dst,
                                                      const int* __restrict__ excl,
                                                      const int* __restrict__ bsum,
                                                      unsigned int* __restrict__ packed,
                                                      int E, int NB, int NBLK) {
    __shared__ int cur[MAXNB];
    const int tid = threadIdx.x;
    const int blk = blockIdx.x;
    for (int b = tid; b < NB; b += 256) {
        size_t p = (size_t)b * NBLK + blk;
        cur[b] = excl[p] + bsum[p >> 11];
    }
    __syncthreads();
    const int base = blk * CHUNK;
    int lim = base + CHUNK; if (lim > E) lim = E;
    for (int i = base + tid; i < lim; i += 256) {
        int d = dst[i];
        int s = src[i];
        int pos = atomicAdd(&cur[d >> BSH], 1);  // LDS atomic only
        packed[pos] = (unsigned)s | ((unsigned)(d & (BWD - 1)) << 26);
    }
}

// One block per bucket: in-bucket per-node counts -> rowptr + dinv + node-grouped col.
__global__ __launch_bounds__(256) void bucket_to_csr(const unsigned int* __restrict__ packed,
                                                     const int* __restrict__ excl,
                                                     const int* __restrict__ bsum,
                                                     int* __restrict__ rowptr,
                                                     float* __restrict__ dinv,
                                                     int* __restrict__ col,
                                                     int E, int N, int NB, int NBLK) {
    __shared__ int cnt[BWD];
    __shared__ int offs[BWD];
    const int b = blockIdx.x;
    const int tid = threadIdx.x;
    size_t p0 = (size_t)b * NBLK;
    const int base = excl[p0] + bsum[p0 >> 11];
    int next;
    if (b + 1 < NB) {
        size_t p1 = (size_t)(b + 1) * NBLK;
        next = excl[p1] + bsum[p1 >> 11];
    } else {
        next = E;
    }
    if (tid < BWD) cnt[tid] = 0;
    __syncthreads();
    for (int i = base + tid; i < next; i += 256) atomicAdd(&cnt[packed[i] >> 26], 1);
    __syncthreads();
    if (tid == 0) {
        int run = 0;
        for (int j = 0; j < BWD; ++j) { offs[j] = run; run += cnt[j]; }
    }
    __syncthreads();
    if (tid < BWD) {
        int node = (b << BSH) + tid;
        if (node < N) {
            rowptr[node] = base + offs[tid];
            dinv[node] = rsqrtf((float)cnt[tid] + 1.0f);
        }
        cnt[tid] = offs[tid];  // reuse as in-bucket cursors
    }
    if (b == NB - 1 && tid == 0) rowptr[N] = E;
    __syncthreads();
    for (int i = base + tid; i < next; i += 256) {
        unsigned int u = packed[i];
        int j = u >> 26;
        int pos = base + atomicAdd(&cnt[j], 1);  // LDS atomic only
        col[pos] = (int)(u & 0x03ffffffu);
    }
}

// ---------------------------------------------------------------------------
// prep_w: W (128x128 fp32, [k][n]) -> bf16 transposed Wsw[n][k]. block 0: W1, 1: W2.
__global__ __launch_bounds__(256) void prep_w(const float* __restrict__ W1,
                                              const float* __restrict__ W2,
                                              unsigned short* __restrict__ wsw1,
                                              unsigned short* __restrict__ wsw2) {
    const float* W = blockIdx.x ? W2 : W1;
    unsigned short* O = blockIdx.x ? wsw2 : wsw1;
    for (int idx = threadIdx.x; idx < 16384; idx += 256) {
        int k = idx >> 7, nn = idx & 127;
        O[nn * 128 + k] = (unsigned short)(bfpack(W[idx], 0.f) & 0xffffu);
    }
}

// ---------------------------------------------------------------------------
// MFMA GEMM: Out[r] = fp8((X[r] @ W) * rowscale[r]).  64 rows x 128 cols per
// block, K=128, v_mfma_f32_16x16x32_bf16. LDS rows padded +8 halfs (272 B
// stride = bank spread 4, 2-way aliasing = free).
// Layouts (m89/m120-verified): A: m=lane&15, k=quad*8+j. B: n=lane&15,
// k=quad*8+j. C/D: col=lane&15, row=quad*4+reg.
#define LDA 136
template <bool BF16IN>
__global__ __launch_bounds__(256, 2) void gemm_mfma(const void* __restrict__ Xv,
                                                    const unsigned short* __restrict__ wsw,
                                                    const float* __restrict__ rowscale,
                                                    unsigned char* __restrict__ Out, int n) {
    __shared__ short sA[64 * LDA];   // 17 KB
    __shared__ short sB[128 * LDA];  // 34 KB
    const int tid = threadIdx.x;
    const int rbase = blockIdx.x * 64;
    int rows = n - rbase; if (rows > 64) rows = 64;

    // stage X tile -> bf16 LDS
    if (BF16IN) {
        const uint4* X4 = (const uint4*)((const unsigned short*)Xv + (size_t)rbase * 128);
        #pragma unroll
        for (int i = 0; i < 4; ++i) {
            int idx = tid + i * 256;             // 1024 uint4 = 64 rows x 16
            int row = idx >> 4, c8 = idx & 15;
            uint4 v = (row < rows) ? X4[idx] : make_uint4(0, 0, 0, 0);
            *(uint4*)(&sA[row * LDA + c8 * 8]) = v;
        }
    } else {
        const float4* X4 = (const float4*)((const float*)Xv + (size_t)rbase * 128);
        #pragma unroll
        for (int i = 0; i < 8; ++i) {
            int idx = tid + i * 256;             // 2048 float4 = 64 rows x 32
            int row = idx >> 5, c = idx & 31;
            float4 v = (row < rows) ? X4[idx] : make_float4(0.f, 0.f, 0.f, 0.f);
            uint2 p = make_uint2(bfpack(v.x, v.y), bfpack(v.z, v.w));
            *(uint2*)(&sA[row * LDA + c * 4]) = p;
        }
    }
    // stage Wsw (bf16 [n][k], dense) -> LDS
    {
        const uint4* W4 = (const uint4*)wsw;
        #pragma unroll
        for (int i = 0; i < 8; ++i) {
            int idx = tid + i * 256;             // 2048 uint4 = 128 rows x 16
            int row = idx >> 4, c8 = idx & 15;
            *(uint4*)(&sB[row * LDA + c8 * 8]) = W4[idx];
        }
    }
    __syncthreads();

    const int w = tid >> 6;
    const int lane = tid & 63;
    const int q = lane >> 4;
    const int m15 = lane & 15;

    v4f acc[8];
    #pragma unroll
    for (int nt = 0; nt < 8; ++nt) acc[nt] = (v4f){0.f, 0.f, 0.f, 0.f};

    v8s a[4];
    const short* pa = sA + (w * 16 + m15) * LDA + q * 8;
    #pragma unroll
    for (int kk = 0; kk < 4; ++kk) a[kk] = *(const v8s*)(pa + kk * 32);

    #pragma unroll
    for (int nt = 0; nt < 8; ++nt) {
        const short* pb = sB + (nt * 16 + m15) * LDA + q * 8;
        #pragma unroll
        for (int kk = 0; kk < 4; ++kk) {
            v8s b = *(const v8s*)(pb + kk * 32);
            acc[nt] = __builtin_amdgcn_mfma_f32_16x16x32_bf16(a[kk], b, acc[nt], 0, 0, 0);
        }
    }

    #pragma unroll
    for (int reg = 0; reg < 4; ++reg) {
        int row = rbase + w * 16 + q * 4 + reg;
        if (row < n) {
            float sc = rowscale[row];
            unsigned char* orow = Out + (size_t)row * 128 + m15;
            #pragma unroll
            for (int nt = 0; nt < 8; ++nt)
                orow[nt * 16] = fp8_enc_byte(acc[nt][reg] * sc);
        }
    }
}

// ---------------------------------------------------------------------------
// Fused CSR gather + epilogue on pre-scaled fp8 T' = (X@W)*dinv[row]:
//   h[d] = relu( (sum_{s in in(d)} T'[s] + T'[d]) * dinv[d] + bias )
// One wave per dst node; each HALF-wave processes alternating edges (row=128B);
// 4 edges in flight per half-wave; cross-half combine via shfl_xor(32).
__global__ __launch_bounds__(256) void gather_fused(const unsigned int* __restrict__ T8,
                                                    const int* __restrict__ rowptr,
                                                    const int* __restrict__ col,
                                                    const float* __restrict__ dinv,
                                                    const float* __restrict__ bias,
                                                    unsigned int* __restrict__ H, int n) {
    const int d = (blockIdx.x * 256 + threadIdx.x) >> 6;
    const int lane = threadIdx.x & 63;
    if (d >= n) return;
    const int half = lane >> 5, sl = lane & 31;
    const int start = rowptr[d], end = rowptr[d + 1];

    float a0 = 0.f, a1 = 0.f, a2 = 0.f, a3 = 0.f;
    float b0 = 0.f, b1 = 0.f, b2 = 0.f, b3 = 0.f;
    int e = start + half;
    for (; e + 6 < end; e += 8) {  // 4 edges in flight per half-wave
        int c0 = col[e], c1 = col[e + 2], c2 = col[e + 4], c3 = col[e + 6];
        unsigned int u0 = T8[(size_t)c0 * 32 + sl];
        unsigned int u1 = T8[(size_t)c1 * 32 + sl];
        unsigned int u2 = T8[(size_t)c2 * 32 + sl];
        unsigned int u3 = T8[(size_t)c3 * 32 + sl];
        float4 f0 = fp8x4_dec(u0), f1 = fp8x4_dec(u1);
        float4 f2 = fp8x4_dec(u2), f3 = fp8x4_dec(u3);
        a0 += f0.x + f1.x; a1 += f0.y + f1.y; a2 += f0.z + f1.z; a3 += f0.w + f1.w;
        b0 += f2.x + f3.x; b1 += f2.y + f3.y; b2 += f2.z + f3.z; b3 += f2.w + f3.w;
    }
    for (; e < end; e += 2) {
        float4 f = fp8x4_dec(T8[(size_t)col[e] * 32 + sl]);
        a0 += f.x; a1 += f.y; a2 += f.z; a3 += f.w;
    }
    a0 += b0; a1 += b1; a2 += b2; a3 += b3;
    // combine the two half-wave partial sums (lane l <-> l^32 hold same cols)
    a0 += __shfl_xor(a0, 32);
    a1 += __shfl_xor(a1, 32);
    a2 += __shfl_xor(a2, 32);
    a3 += __shfl_xor(a3, 32);

    float4 sf = fp8x4_dec(T8[(size_t)d * 32 + sl]);
    const float di = dinv[d];
    const float2 bv = ((const float2*)bias)[2 * sl + half];
    float c0, c1;
    if (half == 0) { c0 = a0 + sf.x; c1 = a1 + sf.y; }
    else           { c0 = a2 + sf.z; c1 = a3 + sf.w; }
    float o0 = fmaxf(fmaf(c0, di, bv.x), 0.f);
    float o1 = fmaxf(fmaf(c1, di, bv.y), 0.f);
    H[(size_t)d * 64 + 2 * sl + half] = bfpack(o0, o1);
}

// ---------------------------------------------------------------------------
__global__ void graph_bounds(const int* __restrict__ batch, int* __restrict__ gstart,
                             int n, int G) {
    int g = blockIdx.x * 128 + threadIdx.x;
    if (g > G) return;
    int lo = 0, hi = n;
    while (lo < hi) { int mid = (lo + hi) >> 1; if (batch[mid] < g) lo = mid + 1; else hi = mid; }
    gstart[g] = lo;
}

// Parallel partial-sum pool over bf16 h (batch sorted -> per-thread running acc)
__global__ __launch_bounds__(256) void pool_partial(const unsigned short* __restrict__ h,
                                                    const int* __restrict__ batch,
                                                    float* __restrict__ pooled, int n) {
    const int c = threadIdx.x & 127;
    const int half = threadIdx.x >> 7;
    int r = blockIdx.x * PCH + half;
    int rend = blockIdx.x * PCH + PCH;
    if (rend > n) rend = n;
    float acc = 0.f;
    int cur = -1;
    for (; r < rend; r += 2) {
        int g = batch[r];
        if (g != cur) {
            if (cur >= 0) atomicAdd(&pooled[(size_t)cur * 128 + c], acc);
            acc = 0.f;
            cur = g;
        }
        acc += __builtin_bit_cast(float, (unsigned int)h[(size_t)r * 128 + c] << 16);
    }
    if (cur >= 0) atomicAdd(&pooled[(size_t)cur * 128 + c], acc);
}

// ---------------------------------------------------------------------------
// out layout: [G*A action_mean][A std][G value]
__global__ void head_kernel(const float* __restrict__ pooled, const int* __restrict__ gstart,
                            const float* __restrict__ Wa, const float* __restrict__ ba,
                            const float* __restrict__ Wv, const float* __restrict__ bv,
                            const float* __restrict__ log_std, float* __restrict__ out, int G) {
    int g = blockIdx.x;
    int t = threadIdx.x;  // 64
    __shared__ float sp[128];
    float inv = 1.0f / fmaxf((float)(gstart[g + 1] - gstart[g]), 1.0f);
    sp[t] = pooled[(size_t)g * 128 + t] * inv;
    sp[t + 64] = pooled[(size_t)g * 128 + 64 + t] * inv;
    __syncthreads();
    if (t < 32) {
        float s = 0.f;
        #pragma unroll 8
        for (int k = 0; k < 128; ++k) s = fmaf(sp[k], Wa[k * ADIM + t], s);
        out[g * ADIM + t] = s + ba[t];
        if (g == 0) out[G * ADIM + t] = expf(log_std[t]);
    } else if (t == 32) {
        float s = 0.f;
        #pragma unroll 8
        for (int k = 0; k < 128; ++k) s = fmaf(sp[k], Wv[k], s);
        out[G * ADIM + ADIM + g] = s + bv[0];
    }
}

// ---------------------------------------------------------------------------
extern "C" void kernel_launch(void* const* d_in, const int* in_sizes, int n_in,
                              void* d_out, int out_size, void* d_ws, size_t ws_size,
                              hipStream_t stream) {
    const float* x       = (const float*)d_in[0];
    const int*   ei      = (const int*)d_in[1];
    const int*   batch   = (const int*)d_in[2];
    const float* W1      = (const float*)d_in[3];
    const float* b1      = (const float*)d_in[4];
    const float* W2      = (const float*)d_in[5];
    const float* b2      = (const float*)d_in[6];
    const float* Wa      = (const float*)d_in[7];
    const float* ba      = (const float*)d_in[8];
    const float* Wv      = (const float*)d_in[9];
    const float* bv      = (const float*)d_in[10];
    const float* log_std = (const float*)d_in[11];
    float* out = (float*)d_out;

    const int N = in_sizes[0] / FDIM;
    const int E = in_sizes[1] / 2;
    const int G = (out_size - ADIM) / (ADIM + 1);
    const int NB = (N + BWD - 1) >> BSH;          // buckets (<= MAXNB for N <= 131072)
    const int NBLK = (E + CHUNK - 1) / CHUNK;     // binning blocks
    const int M = NB * NBLK;                      // scan length
    const int nscanA = (M + 2047) / 2048;         // <= 256

    const int* src = ei;
    const int* dst = ei + E;

    auto align = [](size_t v) { return (v + 255) & ~(size_t)255; };
    char* ws = (char*)d_ws;
    size_t off = 0;
    int*   hist   = (int*)(ws + off);   off = align(off + (size_t)M * 4);
    int*   excl   = (int*)(ws + off);   off = align(off + (size_t)M * 4);
    int*   bsum   = (int*)(ws + off);   off = align(off + (size_t)256 * 4);
    int*   rowptr = (int*)(ws + off);   off = align(off + (size_t)(N + 1) * 4);
    int*   gstart = (int*)(ws + off);   off = align(off + (size_t)(G + 1) * 4);
    float* dinv   = (float*)(ws + off); off = align(off + (size_t)N * 4);
    float* pooled = (float*)(ws + off); off = align(off + (size_t)G * HDIM * 4);
    unsigned short* wsw1 = (unsigned short*)(ws + off); off = align(off + (size_t)16384 * 2);
    unsigned short* wsw2 = (unsigned short*)(ws + off); off = align(off + (size_t)16384 * 2);
    unsigned int* packed = (unsigned int*)(ws + off); off = align(off + (size_t)E * 4);
    int*   col    = (int*)(ws + off);   off = align(off + (size_t)E * 4);
    unsigned int* bufA = (unsigned int*)(ws + off); off = align(off + (size_t)N * 32 * 4);  // fp8 N x 128
    unsigned int* bufB = (unsigned int*)(ws + off); off = align(off + (size_t)N * 64 * 4);  // bf16 N x 128
    (void)ws_size;

    const int blkGemm = (N + 63) / 64;
    const int blkGather = (int)(((long long)N * 64 + 255) / 256);
    const int blkPool = (N + PCH - 1) / PCH;

    // ---- binning -> CSR + dinv (no global atomics) + weight prep ----
    block_hist<<<NBLK, 256, 0, stream>>>(dst, hist, E, NB);
    scanA<<<nscanA, 256, 0, stream>>>(hist, excl, bsum, M, NB, NBLK);
    scanB<<<1, 256, 0, stream>>>(bsum, nscanA);
    bucket_scatter<<<NBLK, 256, 0, stream>>>(src, dst, excl, bsum, packed, E, NB, NBLK);
    bucket_to_csr<<<NB, 256, 0, stream>>>(packed, excl, bsum, rowptr, dinv, col, E, N, NB, NBLK);
    prep_w<<<2, 256, 0, stream>>>(W1, W2, wsw1, wsw2);
    graph_bounds<<<1, 128, 0, stream>>>(batch, gstart, N, G);

    // ---- layer 1 (fp32 in, fp8 out) ----
    gemm_mfma<false><<<blkGemm, 256, 0, stream>>>(x, wsw1, dinv, (unsigned char*)bufA, N);
    gather_fused<<<blkGather, 256, 0, stream>>>(bufA, rowptr, col, dinv, b1, bufB, N);

    // ---- layer 2 (bf16 in, fp8 out) ----
    gemm_mfma<true><<<blkGemm, 256, 0, stream>>>(bufB, wsw2, dinv, (unsigned char*)bufA, N);
    gather_fused<<<blkGather, 256, 0, stream>>>(bufA, rowptr, col, dinv, b2, bufB, N);

    // ---- pool + heads ----
    hipMemsetAsync(pooled, 0, (size_t)G * HDIM * 4, stream);
    pool_partial<<<blkPool, 256, 0, stream>>>((const unsigned short*)bufB, batch, pooled, N);
    head_kernel<<<G, 64, 0, stream>>>(pooled, gstart, Wa, ba, Wv, bv, log_std, out, G);
}

// Round 9
// 357.991 us; speedup vs baseline: 8.7848x; 1.0141x over previous
//
#include <hip/hip_runtime.h>
#include <hip/hip_bf16.h>

#define FDIM 128
#define HDIM 128
#define ADIM 32
#define PCH 128      // rows per pool block
#define BSH 6        // bucket shift: 64 dst nodes per bucket
#define BWD 64
#define CHUNK 8192   // edges per binning block
#define MAXNB 2048   // max buckets supported (N <= 131072)

// Storage permutation for T'/H rows: byte position p holds col c(p).
// p = m15*8 + nt  <->  col = nt*16 + m15 ;  c(p) = ((p&7)<<4) | (p>>3)
#define CP(p) ((((p) & 7) << 4) | ((p) >> 3))

typedef short v8s __attribute__((ext_vector_type(8)));
typedef float v4f __attribute__((ext_vector_type(4)));
typedef float v2f __attribute__((ext_vector_type(2)));

// bf16x2 helpers (bitwise; bf16->fp32 exact, fp32->bf16 RNE)
static __device__ __forceinline__ float bflo(unsigned int u) {
    return __builtin_bit_cast(float, u << 16);
}
static __device__ __forceinline__ float bfhi(unsigned int u) {
    return __builtin_bit_cast(float, u & 0xffff0000u);
}
static __device__ __forceinline__ unsigned int bfpack(float a, float b) {
    unsigned int ua = __builtin_bit_cast(unsigned int, a);
    unsigned int ub = __builtin_bit_cast(unsigned int, b);
    ua += 0x7fffu + ((ua >> 16) & 1u);
    ub += 0x7fffu + ((ub >> 16) & 1u);
    return (ua >> 16) | (ub & 0xffff0000u);
}

// ---------------------------------------------------------------------------
// fp8 e4m3 (OCP) helpers. HW path: gfx950 cvt instructions.
#if defined(__has_builtin) && __has_builtin(__builtin_amdgcn_cvt_pk_f32_fp8) && \
    __has_builtin(__builtin_amdgcn_cvt_pk_fp8_f32)
#define FP8_HW 1
#endif

static __device__ __forceinline__ float4 fp8x4_dec(unsigned int u) {
#ifdef FP8_HW
    v2f lo = __builtin_amdgcn_cvt_pk_f32_fp8(u, false);
    v2f hi = __builtin_amdgcn_cvt_pk_f32_fp8(u, true);
    return make_float4(lo.x, lo.y, hi.x, hi.y);
#else
    float r[4];
    #pragma unroll
    for (int i = 0; i < 4; ++i) {
        unsigned b = (u >> (8 * i)) & 0xffu;
        unsigned s = b >> 7, e = (b >> 3) & 0xfu, m = b & 7u;
        float v = (e == 0) ? (float)m * 0.001953125f
                           : __builtin_bit_cast(float, ((e + 120u) << 23) | (m << 20));
        r[i] = s ? -v : v;
    }
    return make_float4(r[0], r[1], r[2], r[3]);
#endif
}

#ifndef FP8_HW
static __device__ __forceinline__ unsigned int fp8_enc1(float x) {
    unsigned s = __builtin_bit_cast(unsigned, x) >> 31;
    float ax = fabsf(x);
    if (ax > 448.f) return (s << 7) | 0x7Eu;
    if (ax < 0.0009765625f) return s << 7;
    int e2 = (int)((__builtin_bit_cast(unsigned, ax) >> 23) & 0xff) - 127;
    int qe = (e2 < -6 ? -6 : e2) - 3;
    float q = __builtin_bit_cast(float, (unsigned)((qe + 127) << 23));
    float r = rintf(ax / q) * q;
    if (r > 448.f) return (s << 7) | 0x7Eu;
    if (r < 0.001953125f) return s << 7;
    unsigned ub = __builtin_bit_cast(unsigned, r);
    int re = (int)((ub >> 23) & 0xff) - 127;
    if (re < -6) {
        unsigned m = (unsigned)rintf(r * 512.f);
        return (s << 7) | m;
    }
    return (s << 7) | ((unsigned)(re + 7) << 3) | ((ub >> 20) & 7u);
}
#endif

// pack 4 floats -> 4 fp8 bytes in one dword (byte i = value i)
static __device__ __forceinline__ unsigned int fp8x4_enc(float a, float b, float c, float d) {
#ifdef FP8_HW
    int p = __builtin_amdgcn_cvt_pk_fp8_f32(a, b, 0, false);
    p = __builtin_amdgcn_cvt_pk_fp8_f32(c, d, p, true);
    return (unsigned int)p;
#else
    return fp8_enc1(a) | (fp8_enc1(b) << 8) | (fp8_enc1(c) << 16) | (fp8_enc1(d) << 24);
#endif
}

// ---------------------------------------------------------------------------
// Per-block LDS bucket histogram; dense coalesced dump (NO global atomics).
__global__ __launch_bounds__(256) void block_hist(const int* __restrict__ dst,
                                                  int* __restrict__ hist,  // [nblk][NB]
                                                  int E, int NB) {
    __shared__ int h[MAXNB];
    const int tid = threadIdx.x;
    for (int i = tid; i < NB; i += 256) h[i] = 0;
    __syncthreads();
    const int base = blockIdx.x * CHUNK;
    int lim = base + CHUNK; if (lim > E) lim = E;
    for (int i = base + tid; i < lim; i += 256) atomicAdd(&h[dst[i] >> BSH], 1);
    __syncthreads();
    int* hrow = hist + (size_t)blockIdx.x * NB;
    for (int b = tid; b < NB; b += 256) hrow[b] = h[b];
}

// Exclusive scan over M = NB*NBLK counts in bucket-major order.
__global__ void scanA(const int* __restrict__ hist, int* __restrict__ excl,
                      int* __restrict__ bsum, int M, int NB, int NBLK) {
    __shared__ int tmp[256];
    const int t = threadIdx.x;
    const int idx = blockIdx.x * 2048 + t * 8;
    int v[8], s = 0;
    #pragma unroll
    for (int i = 0; i < 8; ++i) {
        int p = idx + i;
        v[i] = (p < M) ? hist[(size_t)(p % NBLK) * NB + (p / NBLK)] : 0;
        s += v[i];
    }
    tmp[t] = s;
    __syncthreads();
    for (int off = 1; off < 256; off <<= 1) {
        int x = (t >= off) ? tmp[t - off] : 0;
        __syncthreads();
        tmp[t] += x;
        __syncthreads();
    }
    int run = tmp[t] - s;
    #pragma unroll
    for (int i = 0; i < 8; ++i) {
        int p = idx + i;
        if (p < M) excl[p] = run;
        run += v[i];
    }
    if (t == 255) bsum[blockIdx.x] = tmp[255];
}

__global__ void scanB(int* __restrict__ bsum, int nb) {
    __shared__ int tmp[256];
    const int t = threadIdx.x;
    int s = (t < nb) ? bsum[t] : 0;
    tmp[t] = s;
    __syncthreads();
    for (int off = 1; off < 256; off <<= 1) {
        int x = (t >= off) ? tmp[t - off] : 0;
        __syncthreads();
        tmp[t] += x;
        __syncthreads();
    }
    if (t < nb) bsum[t] = tmp[t] - s;
}

// Re-read edges; exact LDS cursors from scanned hist (+bsum fixup folded in);
// write packed edge (src | node-in-bucket<<26) grouped by bucket.
__global__ __launch_bounds__(256) void bucket_scatter(const int* __restrict__ src,
                                                      const int* __restrict__ dst,
                                                      const int* __restrict__ excl,
                                                      const int* __restrict__ bsum,
                                                      unsigned int* __restrict__ packed,
                                                      int E, int NB, int NBLK) {
    __shared__ int cur[MAXNB];
    const int tid = threadIdx.x;
    const int blk = blockIdx.x;
    for (int b = tid; b < NB; b += 256) {
        size_t p = (size_t)b * NBLK + blk;
        cur[b] = excl[p] + bsum[p >> 11];
    }
    __syncthreads();
    const int base = blk * CHUNK;
    int lim = base + CHUNK; if (lim > E) lim = E;
    for (int i = base + tid; i < lim; i += 256) {
        int d = dst[i];
        int s = src[i];
        int pos = atomicAdd(&cur[d >> BSH], 1);  // LDS atomic only
        packed[pos] = (unsigned)s | ((unsigned)(d & (BWD - 1)) << 26);
    }
}

// One block per bucket: in-bucket per-node counts -> rowptr + dinv + node-grouped col.
__global__ __launch_bounds__(256) void bucket_to_csr(const unsigned int* __restrict__ packed,
                                                     const int* __restrict__ excl,
                                                     const int* __restrict__ bsum,
                                                     int* __restrict__ rowptr,
                                                     float* __restrict__ dinv,
                                                     int* __restrict__ col,
                                                     int E, int N, int NB, int NBLK) {
    __shared__ int cnt[BWD];
    __shared__ int offs[BWD];
    const int b = blockIdx.x;
    const int tid = threadIdx.x;
    size_t p0 = (size_t)b * NBLK;
    const int base = excl[p0] + bsum[p0 >> 11];
    int next;
    if (b + 1 < NB) {
        size_t p1 = (size_t)(b + 1) * NBLK;
        next = excl[p1] + bsum[p1 >> 11];
    } else {
        next = E;
    }
    if (tid < BWD) cnt[tid] = 0;
    __syncthreads();
    for (int i = base + tid; i < next; i += 256) atomicAdd(&cnt[packed[i] >> 26], 1);
    __syncthreads();
    if (tid == 0) {
        int run = 0;
        for (int j = 0; j < BWD; ++j) { offs[j] = run; run += cnt[j]; }
    }
    __syncthreads();
    if (tid < BWD) {
        int node = (b << BSH) + tid;
        if (node < N) {
            rowptr[node] = base + offs[tid];
            dinv[node] = rsqrtf((float)cnt[tid] + 1.0f);
        }
        cnt[tid] = offs[tid];  // reuse as in-bucket cursors
    }
    if (b == NB - 1 && tid == 0) rowptr[N] = E;
    __syncthreads();
    for (int i = base + tid; i < next; i += 256) {
        unsigned int u = packed[i];
        int j = u >> 26;
        int pos = base + atomicAdd(&cnt[j], 1);  // LDS atomic only
        col[pos] = (int)(u & 0x03ffffffu);
    }
}

// ---------------------------------------------------------------------------
// prep: W1 -> bf16 [n][k] natural; W2 -> bf16 [n][p] with k rows permuted by
// c(p) (matches permuted H layout); biases pre-permuted: pb[p] = b[c(p)].
__global__ __launch_bounds__(256) void prep_w(const float* __restrict__ W1,
                                              const float* __restrict__ W2,
                                              const float* __restrict__ b1,
                                              const float* __restrict__ b2,
                                              unsigned short* __restrict__ wsw1,
                                              unsigned short* __restrict__ wsw2,
                                              float* __restrict__ pb1,
                                              float* __restrict__ pb2) {
    for (int idx = threadIdx.x; idx < 16384; idx += 256) {
        int nn = idx >> 7, k = idx & 127;
        wsw1[idx] = (unsigned short)(bfpack(W1[k * 128 + nn], 0.f) & 0xffffu);
        wsw2[idx] = (unsigned short)(bfpack(W2[CP(k) * 128 + nn], 0.f) & 0xffffu);
    }
    if (threadIdx.x < 128) {
        pb1[threadIdx.x] = b1[CP(threadIdx.x)];
        pb2[threadIdx.x] = b2[CP(threadIdx.x)];
    }
}

// ---------------------------------------------------------------------------
// MFMA GEMM: Out[r] = fp8((X[r] @ W) * rowscale[r]), output cols stored in
// P-order (byte p = m15*8+nt), so each lane's 8 bytes are CONTIGUOUS ->
// paired cvt_pk_fp8 + coalesced dwordx2 stores.
// Layouts (m89/m120-verified): A: m=lane&15, k=quad*8+j. B: n=lane&15,
// k=quad*8+j. C/D: col=lane&15, row=quad*4+reg.
#define LDA 136
template <bool BF16IN>
__global__ __launch_bounds__(256, 2) void gemm_mfma(const void* __restrict__ Xv,
                                                    const unsigned short* __restrict__ wsw,
                                                    const float* __restrict__ rowscale,
                                                    unsigned int* __restrict__ Out, int n) {
    __shared__ short sA[64 * LDA];   // 17 KB
    __shared__ short sB[128 * LDA];  // 34 KB
    const int tid = threadIdx.x;
    const int rbase = blockIdx.x * 64;
    int rows = n - rbase; if (rows > 64) rows = 64;

    // stage X tile -> bf16 LDS
    if (BF16IN) {
        const uint4* X4 = (const uint4*)((const unsigned short*)Xv + (size_t)rbase * 128);
        #pragma unroll
        for (int i = 0; i < 4; ++i) {
            int idx = tid + i * 256;             // 1024 uint4 = 64 rows x 16
            int row = idx >> 4, c8 = idx & 15;
            uint4 v = (row < rows) ? X4[idx] : make_uint4(0, 0, 0, 0);
            *(uint4*)(&sA[row * LDA + c8 * 8]) = v;
        }
    } else {
        const float4* X4 = (const float4*)((const float*)Xv + (size_t)rbase * 128);
        #pragma unroll
        for (int i = 0; i < 8; ++i) {
            int idx = tid + i * 256;             // 2048 float4 = 64 rows x 32
            int row = idx >> 5, c = idx & 31;
            float4 v = (row < rows) ? X4[idx] : make_float4(0.f, 0.f, 0.f, 0.f);
            uint2 p = make_uint2(bfpack(v.x, v.y), bfpack(v.z, v.w));
            *(uint2*)(&sA[row * LDA + c * 4]) = p;
        }
    }
    // stage Wsw (bf16 [n][k], dense) -> LDS
    {
        const uint4* W4 = (const uint4*)wsw;
        #pragma unroll
        for (int i = 0; i < 8; ++i) {
            int idx = tid + i * 256;             // 2048 uint4 = 128 rows x 16
            int row = idx >> 4, c8 = idx & 15;
            *(uint4*)(&sB[row * LDA + c8 * 8]) = W4[idx];
        }
    }
    __syncthreads();

    const int w = tid >> 6;
    const int lane = tid & 63;
    const int q = lane >> 4;
    const int m15 = lane & 15;

    v4f acc[8];
    #pragma unroll
    for (int nt = 0; nt < 8; ++nt) acc[nt] = (v4f){0.f, 0.f, 0.f, 0.f};

    v8s a[4];
    const short* pa = sA + (w * 16 + m15) * LDA + q * 8;
    #pragma unroll
    for (int kk = 0; kk < 4; ++kk) a[kk] = *(const v8s*)(pa + kk * 32);

    #pragma unroll
    for (int nt = 0; nt < 8; ++nt) {
        const short* pb = sB + (nt * 16 + m15) * LDA + q * 8;
        #pragma unroll
        for (int kk = 0; kk < 4; ++kk) {
            v8s b = *(const v8s*)(pb + kk * 32);
            acc[nt] = __builtin_amdgcn_mfma_f32_16x16x32_bf16(a[kk], b, acc[nt], 0, 0, 0);
        }
    }

    // epilogue: row = rbase + w*16 + q*4 + reg; lane writes bytes p=m15*8..+8
    #pragma unroll
    for (int reg = 0; reg < 4; ++reg) {
        int row = rbase + w * 16 + q * 4 + reg;
        if (row < n) {
            float sc = rowscale[row];
            unsigned int d0 = fp8x4_enc(acc[0][reg] * sc, acc[1][reg] * sc,
                                        acc[2][reg] * sc, acc[3][reg] * sc);
            unsigned int d1 = fp8x4_enc(acc[4][reg] * sc, acc[5][reg] * sc,
                                        acc[6][reg] * sc, acc[7][reg] * sc);
            // byte p = m15*8 + nt  ->  dword index = m15*2 (+1)
            Out[(size_t)row * 32 + m15 * 2] = d0;
            Out[(size_t)row * 32 + m15 * 2 + 1] = d1;
        }
    }
}

// ---------------------------------------------------------------------------
// Fused CSR gather + epilogue on pre-scaled fp8 T' (P-ordered rows):
//   h[d] = relu( (sum_{s in in(d)} T'[s] + T'[d]) * dinv[d] + pbias )
// One wave per dst node; each QUARTER-wave (16 lanes x uint2 = 128 B row)
// processes its own edge -> 4 edges per load instr, 16 in flight per wave.
// Cross-quarter combine via shfl_xor(16/32). H written in P-order (bf16).
__global__ __launch_bounds__(256) void gather_fused(const uint2* __restrict__ T8,
                                                    const int* __restrict__ rowptr,
                                                    const int* __restrict__ col,
                                                    const float* __restrict__ dinv,
                                                    const float* __restrict__ pbias,
                                                    uint4* __restrict__ H, int n) {
    const int d = (blockIdx.x * 256 + threadIdx.x) >> 6;
    const int lane = threadIdx.x & 63;
    if (d >= n) return;
    const int q = lane >> 4, ql = lane & 15;
    const int start = rowptr[d], end = rowptr[d + 1];

    float s0 = 0.f, s1 = 0.f, s2 = 0.f, s3 = 0.f;
    float s4 = 0.f, s5 = 0.f, s6 = 0.f, s7 = 0.f;

    int e = start + q;
    for (; e + 12 < end; e += 16) {  // 4 edges per quarter, 16 per wave
        int c0 = col[e], c1 = col[e + 4], c2 = col[e + 8], c3 = col[e + 12];
        uint2 u0 = T8[(size_t)c0 * 16 + ql];
        uint2 u1 = T8[(size_t)c1 * 16 + ql];
        uint2 u2 = T8[(size_t)c2 * 16 + ql];
        uint2 u3 = T8[(size_t)c3 * 16 + ql];
        float4 fa0 = fp8x4_dec(u0.x), fb0 = fp8x4_dec(u0.y);
        float4 fa1 = fp8x4_dec(u1.x), fb1 = fp8x4_dec(u1.y);
        float4 fa2 = fp8x4_dec(u2.x), fb2 = fp8x4_dec(u2.y);
        float4 fa3 = fp8x4_dec(u3.x), fb3 = fp8x4_dec(u3.y);
        s0 += (fa0.x + fa1.x) + (fa2.x + fa3.x);
        s1 += (fa0.y + fa1.y) + (fa2.y + fa3.y);
        s2 += (fa0.z + fa1.z) + (fa2.z + fa3.z);
        s3 += (fa0.w + fa1.w) + (fa2.w + fa3.w);
        s4 += (fb0.x + fb1.x) + (fb2.x + fb3.x);
        s5 += (fb0.y + fb1.y) + (fb2.y + fb3.y);
        s6 += (fb0.z + fb1.z) + (fb2.z + fb3.z);
        s7 += (fb0.w + fb1.w) + (fb2.w + fb3.w);
    }
    for (; e < end; e += 4) {
        uint2 u = T8[(size_t)col[e] * 16 + ql];
        float4 fa = fp8x4_dec(u.x), fb = fp8x4_dec(u.y);
        s0 += fa.x; s1 += fa.y; s2 += fa.z; s3 += fa.w;
        s4 += fb.x; s5 += fb.y; s6 += fb.z; s7 += fb.w;
    }

    // combine quarters (ql preserved; xor 16 and 32 sum all 4 quarters)
    s0 += __shfl_xor(s0, 16); s0 += __shfl_xor(s0, 32);
    s1 += __shfl_xor(s1, 16); s1 += __shfl_xor(s1, 32);
    s2 += __shfl_xor(s2, 16); s2 += __shfl_xor(s2, 32);
    s3 += __shfl_xor(s3, 16); s3 += __shfl_xor(s3, 32);
    s4 += __shfl_xor(s4, 16); s4 += __shfl_xor(s4, 32);
    s5 += __shfl_xor(s5, 16); s5 += __shfl_xor(s5, 32);
    s6 += __shfl_xor(s6, 16); s6 += __shfl_xor(s6, 32);
    s7 += __shfl_xor(s7, 16); s7 += __shfl_xor(s7, 32);

    if (q == 0) {
        uint2 su = T8[(size_t)d * 16 + ql];
        float4 fa = fp8x4_dec(su.x), fb = fp8x4_dec(su.y);
        s0 += fa.x; s1 += fa.y; s2 += fa.z; s3 += fa.w;
        s4 += fb.x; s5 += fb.y; s6 += fb.z; s7 += fb.w;
        const float di = dinv[d];
        const float4* pb4 = (const float4*)pbias;
        float4 b0 = pb4[2 * ql], b1v = pb4[2 * ql + 1];
        float o0 = fmaxf(fmaf(s0, di, b0.x), 0.f);
        float o1 = fmaxf(fmaf(s1, di, b0.y), 0.f);
        float o2 = fmaxf(fmaf(s2, di, b0.z), 0.f);
        float o3 = fmaxf(fmaf(s3, di, b0.w), 0.f);
        float o4 = fmaxf(fmaf(s4, di, b1v.x), 0.f);
        float o5 = fmaxf(fmaf(s5, di, b1v.y), 0.f);
        float o6 = fmaxf(fmaf(s6, di, b1v.z), 0.f);
        float o7 = fmaxf(fmaf(s7, di, b1v.w), 0.f);
        uint4 o;
        o.x = bfpack(o0, o1); o.y = bfpack(o2, o3);
        o.z = bfpack(o4, o5); o.w = bfpack(o6, o7);
        H[(size_t)d * 16 + ql] = o;
    }
}

// ---------------------------------------------------------------------------
__global__ void graph_bounds(const int* __restrict__ batch, int* __restrict__ gstart,
                             int n, int G) {
    int g = blockIdx.x * 128 + threadIdx.x;
    if (g > G) return;
    int lo = 0, hi = n;
    while (lo < hi) { int mid = (lo + hi) >> 1; if (batch[mid] < g) lo = mid + 1; else hi = mid; }
    gstart[g] = lo;
}

// Parallel partial-sum pool over bf16 h (P-ordered cols; pooled is P-ordered)
__global__ __launch_bounds__(256) void pool_partial(const unsigned short* __restrict__ h,
                                                    const int* __restrict__ batch,
                                                    float* __restrict__ pooled, int n) {
    const int c = threadIdx.x & 127;
    const int half = threadIdx.x >> 7;
    int r = blockIdx.x * PCH + half;
    int rend = blockIdx.x * PCH + PCH;
    if (rend > n) rend = n;
    float acc = 0.f;
    int cur = -1;
    for (; r < rend; r += 2) {
        int g = batch[r];
        if (g != cur) {
            if (cur >= 0) atomicAdd(&pooled[(size_t)cur * 128 + c], acc);
            acc = 0.f;
            cur = g;
        }
        acc += __builtin_bit_cast(float, (unsigned int)h[(size_t)r * 128 + c] << 16);
    }
    if (cur >= 0) atomicAdd(&pooled[(size_t)cur * 128 + c], acc);
}

// ---------------------------------------------------------------------------
// out layout: [G*A action_mean][A std][G value]. pooled is P-ordered ->
// index head weights by c(p).
__global__ void head_kernel(const float* __restrict__ pooled, const int* __restrict__ gstart,
                            const float* __restrict__ Wa, const float* __restrict__ ba,
                            const float* __restrict__ Wv, const float* __restrict__ bv,
                            const float* __restrict__ log_std, float* __restrict__ out, int G) {
    int g = blockIdx.x;
    int t = threadIdx.x;  // 64
    __shared__ float sp[128];
    float inv = 1.0f / fmaxf((float)(gstart[g + 1] - gstart[g]), 1.0f);
    sp[t] = pooled[(size_t)g * 128 + t] * inv;
    sp[t + 64] = pooled[(size_t)g * 128 + 64 + t] * inv;
    __syncthreads();
    if (t < 32) {
        float s = 0.f;
        #pragma unroll 8
        for (int k = 0; k < 128; ++k) s = fmaf(sp[k], Wa[CP(k) * ADIM + t], s);
        out[g * ADIM + t] = s + ba[t];
        if (g == 0) out[G * ADIM + t] = expf(log_std[t]);
    } else if (t == 32) {
        float s = 0.f;
        #pragma unroll 8
        for (int k = 0; k < 128; ++k) s = fmaf(sp[k], Wv[CP(k)], s);
        out[G * ADIM + ADIM + g] = s + bv[0];
    }
}

// ---------------------------------------------------------------------------
extern "C" void kernel_launch(void* const* d_in, const int* in_sizes, int n_in,
                              void* d_out, int out_size, void* d_ws, size_t ws_size,
                              hipStream_t stream) {
    const float* x       = (const float*)d_in[0];
    const int*   ei      = (const int*)d_in[1];
    const int*   batch   = (const int*)d_in[2];
    const float* W1      = (const float*)d_in[3];
    const float* b1      = (const float*)d_in[4];
    const float* W2      = (const float*)d_in[5];
    const float* b2      = (const float*)d_in[6];
    const float* Wa      = (const float*)d_in[7];
    const float* ba      = (const float*)d_in[8];
    const float* Wv      = (const float*)d_in[9];
    const float* bv      = (const float*)d_in[10];
    const float* log_std = (const float*)d_in[11];
    float* out = (float*)d_out;

    const int N = in_sizes[0] / FDIM;
    const int E = in_sizes[1] / 2;
    const int G = (out_size - ADIM) / (ADIM + 1);
    const int NB = (N + BWD - 1) >> BSH;          // buckets (<= MAXNB for N <= 131072)
    const int NBLK = (E + CHUNK - 1) / CHUNK;     // binning blocks
    const int M = NB * NBLK;                      // scan length
    const int nscanA = (M + 2047) / 2048;         // <= 256

    const int* src = ei;
    const int* dst = ei + E;

    auto align = [](size_t v) { return (v + 255) & ~(size_t)255; };
    char* ws = (char*)d_ws;
    size_t off = 0;
    int*   hist   = (int*)(ws + off);   off = align(off + (size_t)M * 4);
    int*   excl   = (int*)(ws + off);   off = align(off + (size_t)M * 4);
    int*   bsum   = (int*)(ws + off);   off = align(off + (size_t)256 * 4);
    int*   rowptr = (int*)(ws + off);   off = align(off + (size_t)(N + 1) * 4);
    int*   gstart = (int*)(ws + off);   off = align(off + (size_t)(G + 1) * 4);
    float* dinv   = (float*)(ws + off); off = align(off + (size_t)N * 4);
    float* pooled = (float*)(ws + off); off = align(off + (size_t)G * HDIM * 4);
    unsigned short* wsw1 = (unsigned short*)(ws + off); off = align(off + (size_t)16384 * 2);
    unsigned short* wsw2 = (unsigned short*)(ws + off); off = align(off + (size_t)16384 * 2);
    float* pb1    = (float*)(ws + off); off = align(off + (size_t)128 * 4);
    float* pb2    = (float*)(ws + off); off = align(off + (size_t)128 * 4);
    unsigned int* packed = (unsigned int*)(ws + off); off = align(off + (size_t)E * 4);
    int*   col    = (int*)(ws + off);   off = align(off + (size_t)E * 4);
    unsigned int* bufA = (unsigned int*)(ws + off); off = align(off + (size_t)N * 32 * 4);  // fp8 N x 128 (P-order)
    unsigned int* bufB = (unsigned int*)(ws + off); off = align(off + (size_t)N * 64 * 4);  // bf16 N x 128 (P-order)
    (void)ws_size;

    const int blkGemm = (N + 63) / 64;
    const int blkGather = (int)(((long long)N * 64 + 255) / 256);
    const int blkPool = (N + PCH - 1) / PCH;

    // ---- binning -> CSR + dinv (no global atomics) + weight/bias prep ----
    block_hist<<<NBLK, 256, 0, stream>>>(dst, hist, E, NB);
    scanA<<<nscanA, 256, 0, stream>>>(hist, excl, bsum, M, NB, NBLK);
    scanB<<<1, 256, 0, stream>>>(bsum, nscanA);
    bucket_scatter<<<NBLK, 256, 0, stream>>>(src, dst, excl, bsum, packed, E, NB, NBLK);
    bucket_to_csr<<<NB, 256, 0, stream>>>(packed, excl, bsum, rowptr, dinv, col, E, N, NB, NBLK);
    prep_w<<<1, 256, 0, stream>>>(W1, W2, b1, b2, wsw1, wsw2, pb1, pb2);
    graph_bounds<<<1, 128, 0, stream>>>(batch, gstart, N, G);

    // ---- layer 1 (fp32 in, fp8 P-order out) ----
    gemm_mfma<false><<<blkGemm, 256, 0, stream>>>(x, wsw1, dinv, bufA, N);
    gather_fused<<<blkGather, 256, 0, stream>>>((const uint2*)bufA, rowptr, col, dinv, pb1,
                                                (uint4*)bufB, N);

    // ---- layer 2 (bf16 P-order in, fp8 P-order out) ----
    gemm_mfma<true><<<blkGemm, 256, 0, stream>>>(bufB, wsw2, dinv, bufA, N);
    gather_fused<<<blkGather, 256, 0, stream>>>((const uint2*)bufA, rowptr, col, dinv, pb2,
                                                (uint4*)bufB, N);

    // ---- pool + heads ----
    hipMemsetAsync(pooled, 0, (size_t)G * HDIM * 4, stream);
    pool_partial<<<blkPool, 256, 0, stream>>>((const unsigned short*)bufB, batch, pooled, N);
    head_kernel<<<G, 64, 0, stream>>>(pooled, gstart, Wa, ba, Wv, bv, log_std, out, G);
}

// Round 10
// 357.511 us; speedup vs baseline: 8.7966x; 1.0013x over previous
//
#include <hip/hip_runtime.h>
#include <hip/hip_bf16.h>

#define FDIM 128
#define HDIM 128
#define ADIM 32
#define PCH 128      // rows per pool block
#define BSH 6        // bucket shift: 64 dst nodes per bucket
#define BWD 64
#define CHUNK 8192   // edges per binning block
#define MAXNB 2048   // max buckets supported (N <= 131072)

// Storage permutation for T'/H rows: byte position p holds col c(p).
// p = m15*8 + nt  <->  col = nt*16 + m15 ;  c(p) = ((p&7)<<4) | (p>>3)
#define CP(p) ((((p) & 7) << 4) | ((p) >> 3))

typedef short v8s __attribute__((ext_vector_type(8)));
typedef float v4f __attribute__((ext_vector_type(4)));
typedef float v2f __attribute__((ext_vector_type(2)));

// bf16x2 helpers (bitwise; bf16->fp32 exact, fp32->bf16 RNE)
static __device__ __forceinline__ float bflo(unsigned int u) {
    return __builtin_bit_cast(float, u << 16);
}
static __device__ __forceinline__ float bfhi(unsigned int u) {
    return __builtin_bit_cast(float, u & 0xffff0000u);
}
static __device__ __forceinline__ unsigned int bfpack(float a, float b) {
    unsigned int ua = __builtin_bit_cast(unsigned int, a);
    unsigned int ub = __builtin_bit_cast(unsigned int, b);
    ua += 0x7fffu + ((ua >> 16) & 1u);
    ub += 0x7fffu + ((ub >> 16) & 1u);
    return (ua >> 16) | (ub & 0xffff0000u);
}

// ---------------------------------------------------------------------------
// fp8 e4m3 (OCP) helpers. HW path: gfx950 cvt instructions.
#if defined(__has_builtin) && __has_builtin(__builtin_amdgcn_cvt_pk_f32_fp8) && \
    __has_builtin(__builtin_amdgcn_cvt_pk_fp8_f32)
#define FP8_HW 1
#endif

static __device__ __forceinline__ v2f fp8_dec_lo(unsigned int u) {
#ifdef FP8_HW
    return __builtin_amdgcn_cvt_pk_f32_fp8(u, false);
#else
    v2f r;
    #pragma unroll
    for (int i = 0; i < 2; ++i) {
        unsigned b = (u >> (8 * i)) & 0xffu;
        unsigned s = b >> 7, e = (b >> 3) & 0xfu, m = b & 7u;
        float v = (e == 0) ? (float)m * 0.001953125f
                           : __builtin_bit_cast(float, ((e + 120u) << 23) | (m << 20));
        r[i] = s ? -v : v;
    }
    return r;
#endif
}
static __device__ __forceinline__ v2f fp8_dec_hi(unsigned int u) {
#ifdef FP8_HW
    return __builtin_amdgcn_cvt_pk_f32_fp8(u, true);
#else
    return fp8_dec_lo(u >> 16);
#endif
}

#ifndef FP8_HW
static __device__ __forceinline__ unsigned int fp8_enc1(float x) {
    unsigned s = __builtin_bit_cast(unsigned, x) >> 31;
    float ax = fabsf(x);
    if (ax > 448.f) return (s << 7) | 0x7Eu;
    if (ax < 0.0009765625f) return s << 7;
    int e2 = (int)((__builtin_bit_cast(unsigned, ax) >> 23) & 0xff) - 127;
    int qe = (e2 < -6 ? -6 : e2) - 3;
    float q = __builtin_bit_cast(float, (unsigned)((qe + 127) << 23));
    float r = rintf(ax / q) * q;
    if (r > 448.f) return (s << 7) | 0x7Eu;
    if (r < 0.001953125f) return s << 7;
    unsigned ub = __builtin_bit_cast(unsigned, r);
    int re = (int)((ub >> 23) & 0xff) - 127;
    if (re < -6) {
        unsigned m = (unsigned)rintf(r * 512.f);
        return (s << 7) | m;
    }
    return (s << 7) | ((unsigned)(re + 7) << 3) | ((ub >> 20) & 7u);
}
#endif

// pack 4 floats -> 4 fp8 bytes in one dword (byte i = value i)
static __device__ __forceinline__ unsigned int fp8x4_enc(float a, float b, float c, float d) {
#ifdef FP8_HW
    int p = __builtin_amdgcn_cvt_pk_fp8_f32(a, b, 0, false);
    p = __builtin_amdgcn_cvt_pk_fp8_f32(c, d, p, true);
    return (unsigned int)p;
#else
    return fp8_enc1(a) | (fp8_enc1(b) << 8) | (fp8_enc1(c) << 16) | (fp8_enc1(d) << 24);
#endif
}

// ---------------------------------------------------------------------------
// Per-block LDS bucket histogram; dense coalesced dump (NO global atomics).
__global__ __launch_bounds__(256) void block_hist(const int* __restrict__ dst,
                                                  int* __restrict__ hist,  // [nblk][NB]
                                                  int E, int NB) {
    __shared__ int h[MAXNB];
    const int tid = threadIdx.x;
    for (int i = tid; i < NB; i += 256) h[i] = 0;
    __syncthreads();
    const int base = blockIdx.x * CHUNK;
    int lim = base + CHUNK; if (lim > E) lim = E;
    for (int i = base + tid; i < lim; i += 256) atomicAdd(&h[dst[i] >> BSH], 1);
    __syncthreads();
    int* hrow = hist + (size_t)blockIdx.x * NB;
    for (int b = tid; b < NB; b += 256) hrow[b] = h[b];
}

// Exclusive scan over M = NB*NBLK counts in bucket-major order.
__global__ void scanA(const int* __restrict__ hist, int* __restrict__ excl,
                      int* __restrict__ bsum, int M, int NB, int NBLK) {
    __shared__ int tmp[256];
    const int t = threadIdx.x;
    const int idx = blockIdx.x * 2048 + t * 8;
    int v[8], s = 0;
    #pragma unroll
    for (int i = 0; i < 8; ++i) {
        int p = idx + i;
        v[i] = (p < M) ? hist[(size_t)(p % NBLK) * NB + (p / NBLK)] : 0;
        s += v[i];
    }
    tmp[t] = s;
    __syncthreads();
    for (int off = 1; off < 256; off <<= 1) {
        int x = (t >= off) ? tmp[t - off] : 0;
        __syncthreads();
        tmp[t] += x;
        __syncthreads();
    }
    int run = tmp[t] - s;
    #pragma unroll
    for (int i = 0; i < 8; ++i) {
        int p = idx + i;
        if (p < M) excl[p] = run;
        run += v[i];
    }
    if (t == 255) bsum[blockIdx.x] = tmp[255];
}

__global__ void scanB(int* __restrict__ bsum, int nb) {
    __shared__ int tmp[256];
    const int t = threadIdx.x;
    int s = (t < nb) ? bsum[t] : 0;
    tmp[t] = s;
    __syncthreads();
    for (int off = 1; off < 256; off <<= 1) {
        int x = (t >= off) ? tmp[t - off] : 0;
        __syncthreads();
        tmp[t] += x;
        __syncthreads();
    }
    if (t < nb) bsum[t] = tmp[t] - s;
}

// Re-read edges; exact LDS cursors from scanned hist (+bsum fixup folded in);
// write packed edge (src | node-in-bucket<<26) grouped by bucket.
__global__ __launch_bounds__(256) void bucket_scatter(const int* __restrict__ src,
                                                      const int* __restrict__ dst,
                                                      const int* __restrict__ excl,
                                                      const int* __restrict__ bsum,
                                                      unsigned int* __restrict__ packed,
                                                      int E, int NB, int NBLK) {
    __shared__ int cur[MAXNB];
    const int tid = threadIdx.x;
    const int blk = blockIdx.x;
    for (int b = tid; b < NB; b += 256) {
        size_t p = (size_t)b * NBLK + blk;
        cur[b] = excl[p] + bsum[p >> 11];
    }
    __syncthreads();
    const int base = blk * CHUNK;
    int lim = base + CHUNK; if (lim > E) lim = E;
    for (int i = base + tid; i < lim; i += 256) {
        int d = dst[i];
        int s = src[i];
        int pos = atomicAdd(&cur[d >> BSH], 1);  // LDS atomic only
        packed[pos] = (unsigned)s | ((unsigned)(d & (BWD - 1)) << 26);
    }
}

// One block per bucket: in-bucket per-node counts -> rowptr + dinv + node-grouped col.
__global__ __launch_bounds__(256) void bucket_to_csr(const unsigned int* __restrict__ packed,
                                                     const int* __restrict__ excl,
                                                     const int* __restrict__ bsum,
                                                     int* __restrict__ rowptr,
                                                     float* __restrict__ dinv,
                                                     int* __restrict__ col,
                                                     int E, int N, int NB, int NBLK) {
    __shared__ int cnt[BWD];
    __shared__ int offs[BWD];
    const int b = blockIdx.x;
    const int tid = threadIdx.x;
    size_t p0 = (size_t)b * NBLK;
    const int base = excl[p0] + bsum[p0 >> 11];
    int next;
    if (b + 1 < NB) {
        size_t p1 = (size_t)(b + 1) * NBLK;
        next = excl[p1] + bsum[p1 >> 11];
    } else {
        next = E;
    }
    if (tid < BWD) cnt[tid] = 0;
    __syncthreads();
    for (int i = base + tid; i < next; i += 256) atomicAdd(&cnt[packed[i] >> 26], 1);
    __syncthreads();
    if (tid == 0) {
        int run = 0;
        for (int j = 0; j < BWD; ++j) { offs[j] = run; run += cnt[j]; }
    }
    __syncthreads();
    if (tid < BWD) {
        int node = (b << BSH) + tid;
        if (node < N) {
            rowptr[node] = base + offs[tid];
            dinv[node] = rsqrtf((float)cnt[tid] + 1.0f);
        }
        cnt[tid] = offs[tid];  // reuse as in-bucket cursors
    }
    if (b == NB - 1 && tid == 0) rowptr[N] = E;
    __syncthreads();
    for (int i = base + tid; i < next; i += 256) {
        unsigned int u = packed[i];
        int j = u >> 26;
        int pos = base + atomicAdd(&cnt[j], 1);  // LDS atomic only
        col[pos] = (int)(u & 0x03ffffffu);
    }
}

// ---------------------------------------------------------------------------
// setup_misc: block 0 = weight/bias prep (W -> bf16 [n][k], W2 rows permuted
// by c(p); biases pre-permuted); block 1 = graph_bounds; block 2 = zero pooled.
__global__ __launch_bounds__(256) void setup_misc(const float* __restrict__ W1,
                                                  const float* __restrict__ W2,
                                                  const float* __restrict__ b1,
                                                  const float* __restrict__ b2,
                                                  unsigned short* __restrict__ wsw1,
                                                  unsigned short* __restrict__ wsw2,
                                                  float* __restrict__ pb1,
                                                  float* __restrict__ pb2,
                                                  const int* __restrict__ batch,
                                                  int* __restrict__ gstart,
                                                  float* __restrict__ pooled,
                                                  int n, int G) {
    const int t = threadIdx.x;
    if (blockIdx.x == 0) {
        for (int idx = t; idx < 16384; idx += 256) {
            int nn = idx >> 7, k = idx & 127;
            wsw1[idx] = (unsigned short)(bfpack(W1[k * 128 + nn], 0.f) & 0xffffu);
            wsw2[idx] = (unsigned short)(bfpack(W2[CP(k) * 128 + nn], 0.f) & 0xffffu);
        }
        if (t < 128) {
            pb1[t] = b1[CP(t)];
            pb2[t] = b2[CP(t)];
        }
    } else if (blockIdx.x == 1) {
        if (t <= G) {
            int lo = 0, hi = n;
            while (lo < hi) { int mid = (lo + hi) >> 1; if (batch[mid] < t) lo = mid + 1; else hi = mid; }
            gstart[t] = lo;
        }
    } else {
        for (int i = t; i < G * 128; i += 256) pooled[i] = 0.f;
    }
}

// ---------------------------------------------------------------------------
// MFMA GEMM: Out[r] = fp8((X[r] @ W) * rowscale[r]), output cols in P-order.
// 64 rows x 128 cols per block, K=128, v_mfma_f32_16x16x32_bf16.
// A staged in LDS (17.4 KB -> 4+ blocks/CU); W fragments loaded DIRECTLY from
// the 32 KB L1-resident wsw (no sB stage, no second sync).
// Layouts (m89/m120-verified): A: m=lane&15, k=quad*8+j. B: n=lane&15,
// k=quad*8+j. C/D: col=lane&15, row=quad*4+reg.
#define LDA 136
template <bool BF16IN>
__global__ __launch_bounds__(256, 4) void gemm_mfma(const void* __restrict__ Xv,
                                                    const unsigned short* __restrict__ wsw,
                                                    const float* __restrict__ rowscale,
                                                    unsigned int* __restrict__ Out, int n) {
    __shared__ short sA[64 * LDA];   // 17.4 KB
    const int tid = threadIdx.x;
    const int rbase = blockIdx.x * 64;
    int rows = n - rbase; if (rows > 64) rows = 64;

    // stage X tile -> bf16 LDS
    if (BF16IN) {
        const uint4* X4 = (const uint4*)((const unsigned short*)Xv + (size_t)rbase * 128);
        #pragma unroll
        for (int i = 0; i < 4; ++i) {
            int idx = tid + i * 256;             // 1024 uint4 = 64 rows x 16
            int row = idx >> 4, c8 = idx & 15;
            uint4 v = (row < rows) ? X4[idx] : make_uint4(0, 0, 0, 0);
            *(uint4*)(&sA[row * LDA + c8 * 8]) = v;
        }
    } else {
        const float4* X4 = (const float4*)((const float*)Xv + (size_t)rbase * 128);
        #pragma unroll
        for (int i = 0; i < 8; ++i) {
            int idx = tid + i * 256;             // 2048 float4 = 64 rows x 32
            int row = idx >> 5, c = idx & 31;
            float4 v = (row < rows) ? X4[idx] : make_float4(0.f, 0.f, 0.f, 0.f);
            uint2 p = make_uint2(bfpack(v.x, v.y), bfpack(v.z, v.w));
            *(uint2*)(&sA[row * LDA + c * 4]) = p;
        }
    }
    __syncthreads();

    const int w = tid >> 6;
    const int lane = tid & 63;
    const int q = lane >> 4;
    const int m15 = lane & 15;

    v4f acc[8];
    #pragma unroll
    for (int nt = 0; nt < 8; ++nt) acc[nt] = (v4f){0.f, 0.f, 0.f, 0.f};

    v8s a[4];
    const short* pa = sA + (w * 16 + m15) * LDA + q * 8;
    #pragma unroll
    for (int kk = 0; kk < 4; ++kk) a[kk] = *(const v8s*)(pa + kk * 32);

    const v8s* __restrict__ pW = (const v8s*)wsw;  // fragment idx = row*16 + kk*4 + q
    #pragma unroll
    for (int nt = 0; nt < 8; ++nt) {
        const int base = (nt * 16 + m15) * 16 + q;
        #pragma unroll
        for (int kk = 0; kk < 4; ++kk) {
            v8s b = pW[base + kk * 4];
            acc[nt] = __builtin_amdgcn_mfma_f32_16x16x32_bf16(a[kk], b, acc[nt], 0, 0, 0);
        }
    }

    // epilogue: row = rbase + w*16 + q*4 + reg; lane writes bytes p=m15*8..+8
    #pragma unroll
    for (int reg = 0; reg < 4; ++reg) {
        int row = rbase + w * 16 + q * 4 + reg;
        if (row < n) {
            float sc = rowscale[row];
            unsigned int d0 = fp8x4_enc(acc[0][reg] * sc, acc[1][reg] * sc,
                                        acc[2][reg] * sc, acc[3][reg] * sc);
            unsigned int d1 = fp8x4_enc(acc[4][reg] * sc, acc[5][reg] * sc,
                                        acc[6][reg] * sc, acc[7][reg] * sc);
            Out[(size_t)row * 32 + m15 * 2] = d0;
            Out[(size_t)row * 32 + m15 * 2 + 1] = d1;
        }
    }
}

// ---------------------------------------------------------------------------
// Fused CSR gather + epilogue on pre-scaled fp8 T' (P-ordered rows):
//   h[d] = relu( (sum_{s in in(d)} T'[s] + T'[d]) * dinv[d] + pbias )
// HALF-wave per dst node (32 lanes x 1 dword = 128 B row): no cross-lane
// combine at all; v2f accumulators -> v_pk_add_f32; 8-deep unrolled loads.
__global__ __launch_bounds__(256) void gather_fused(const unsigned int* __restrict__ T32,
                                                    const int* __restrict__ rowptr,
                                                    const int* __restrict__ col,
                                                    const float* __restrict__ dinv,
                                                    const float* __restrict__ pbias,
                                                    uint2* __restrict__ H, int n) {
    const int wave = (blockIdx.x * 256 + threadIdx.x) >> 6;
    const int d = wave * 2 + ((threadIdx.x >> 5) & 1);
    const int hl = threadIdx.x & 31;
    if (d >= n) return;
    const int start = rowptr[d], end = rowptr[d + 1];

    v2f sl0 = {0.f, 0.f}, sh0 = {0.f, 0.f}, sl1 = {0.f, 0.f}, sh1 = {0.f, 0.f};

    int e = start;
    for (; e + 7 < end; e += 8) {
        int c0 = col[e],     c1 = col[e + 1], c2 = col[e + 2], c3 = col[e + 3];
        int c4 = col[e + 4], c5 = col[e + 5], c6 = col[e + 6], c7 = col[e + 7];
        unsigned int u0 = T32[(size_t)c0 * 32 + hl];
        unsigned int u1 = T32[(size_t)c1 * 32 + hl];
        unsigned int u2 = T32[(size_t)c2 * 32 + hl];
        unsigned int u3 = T32[(size_t)c3 * 32 + hl];
        unsigned int u4 = T32[(size_t)c4 * 32 + hl];
        unsigned int u5 = T32[(size_t)c5 * 32 + hl];
        unsigned int u6 = T32[(size_t)c6 * 32 + hl];
        unsigned int u7 = T32[(size_t)c7 * 32 + hl];
        sl0 += fp8_dec_lo(u0); sh0 += fp8_dec_hi(u0);
        sl1 += fp8_dec_lo(u1); sh1 += fp8_dec_hi(u1);
        sl0 += fp8_dec_lo(u2); sh0 += fp8_dec_hi(u2);
        sl1 += fp8_dec_lo(u3); sh1 += fp8_dec_hi(u3);
        sl0 += fp8_dec_lo(u4); sh0 += fp8_dec_hi(u4);
        sl1 += fp8_dec_lo(u5); sh1 += fp8_dec_hi(u5);
        sl0 += fp8_dec_lo(u6); sh0 += fp8_dec_hi(u6);
        sl1 += fp8_dec_lo(u7); sh1 += fp8_dec_hi(u7);
    }
    for (; e + 1 < end; e += 2) {
        int c0 = col[e], c1 = col[e + 1];
        unsigned int u0 = T32[(size_t)c0 * 32 + hl];
        unsigned int u1 = T32[(size_t)c1 * 32 + hl];
        sl0 += fp8_dec_lo(u0); sh0 += fp8_dec_hi(u0);
        sl1 += fp8_dec_lo(u1); sh1 += fp8_dec_hi(u1);
    }
    if (e < end) {
        unsigned int u = T32[(size_t)col[e] * 32 + hl];
        sl0 += fp8_dec_lo(u); sh0 += fp8_dec_hi(u);
    }

    // self term
    unsigned int su = T32[(size_t)d * 32 + hl];
    sl0 += fp8_dec_lo(su); sh0 += fp8_dec_hi(su);
    v2f sl = sl0 + sl1, sh = sh0 + sh1;

    const float di = dinv[d];
    const float4 bv = ((const float4*)pbias)[hl];
    float o0 = fmaxf(fmaf(sl.x, di, bv.x), 0.f);
    float o1 = fmaxf(fmaf(sl.y, di, bv.y), 0.f);
    float o2 = fmaxf(fmaf(sh.x, di, bv.z), 0.f);
    float o3 = fmaxf(fmaf(sh.y, di, bv.w), 0.f);
    uint2 o;
    o.x = bfpack(o0, o1);
    o.y = bfpack(o2, o3);
    H[(size_t)d * 32 + hl] = o;
}

// ---------------------------------------------------------------------------
// Parallel partial-sum pool over bf16 h (P-ordered cols; pooled is P-ordered)
__global__ __launch_bounds__(256) void pool_partial(const unsigned short* __restrict__ h,
                                                    const int* __restrict__ batch,
                                                    float* __restrict__ pooled, int n) {
    const int c = threadIdx.x & 127;
    const int half = threadIdx.x >> 7;
    int r = blockIdx.x * PCH + half;
    int rend = blockIdx.x * PCH + PCH;
    if (rend > n) rend = n;
    float acc = 0.f;
    int cur = -1;
    for (; r < rend; r += 2) {
        int g = batch[r];
        if (g != cur) {
            if (cur >= 0) atomicAdd(&pooled[(size_t)cur * 128 + c], acc);
            acc = 0.f;
            cur = g;
        }
        acc += __builtin_bit_cast(float, (unsigned int)h[(size_t)r * 128 + c] << 16);
    }
    if (cur >= 0) atomicAdd(&pooled[(size_t)cur * 128 + c], acc);
}

// ---------------------------------------------------------------------------
// out layout: [G*A action_mean][A std][G value]. pooled is P-ordered ->
// index head weights by c(p).
__global__ void head_kernel(const float* __restrict__ pooled, const int* __restrict__ gstart,
                            const float* __restrict__ Wa, const float* __restrict__ ba,
                            const float* __restrict__ Wv, const float* __restrict__ bv,
                            const float* __restrict__ log_std, float* __restrict__ out, int G) {
    int g = blockIdx.x;
    int t = threadIdx.x;  // 64
    __shared__ float sp[128];
    float inv = 1.0f / fmaxf((float)(gstart[g + 1] - gstart[g]), 1.0f);
    sp[t] = pooled[(size_t)g * 128 + t] * inv;
    sp[t + 64] = pooled[(size_t)g * 128 + 64 + t] * inv;
    __syncthreads();
    if (t < 32) {
        float s = 0.f;
        #pragma unroll 8
        for (int k = 0; k < 128; ++k) s = fmaf(sp[k], Wa[CP(k) * ADIM + t], s);
        out[g * ADIM + t] = s + ba[t];
        if (g == 0) out[G * ADIM + t] = expf(log_std[t]);
    } else if (t == 32) {
        float s = 0.f;
        #pragma unroll 8
        for (int k = 0; k < 128; ++k) s = fmaf(sp[k], Wv[CP(k)], s);
        out[G * ADIM + ADIM + g] = s + bv[0];
    }
}

// ---------------------------------------------------------------------------
extern "C" void kernel_launch(void* const* d_in, const int* in_sizes, int n_in,
                              void* d_out, int out_size, void* d_ws, size_t ws_size,
                              hipStream_t stream) {
    const float* x       = (const float*)d_in[0];
    const int*   ei      = (const int*)d_in[1];
    const int*   batch   = (const int*)d_in[2];
    const float* W1      = (const float*)d_in[3];
    const float* b1      = (const float*)d_in[4];
    const float* W2      = (const float*)d_in[5];
    const float* b2      = (const float*)d_in[6];
    const float* Wa      = (const float*)d_in[7];
    const float* ba      = (const float*)d_in[8];
    const float* Wv      = (const float*)d_in[9];
    const float* bv      = (const float*)d_in[10];
    const float* log_std = (const float*)d_in[11];
    float* out = (float*)d_out;

    const int N = in_sizes[0] / FDIM;
    const int E = in_sizes[1] / 2;
    const int G = (out_size - ADIM) / (ADIM + 1);
    const int NB = (N + BWD - 1) >> BSH;          // buckets (<= MAXNB for N <= 131072)
    const int NBLK = (E + CHUNK - 1) / CHUNK;     // binning blocks
    const int M = NB * NBLK;                      // scan length
    const int nscanA = (M + 2047) / 2048;         // <= 256

    const int* src = ei;
    const int* dst = ei + E;

    auto align = [](size_t v) { return (v + 255) & ~(size_t)255; };
    char* ws = (char*)d_ws;
    size_t off = 0;
    int*   hist   = (int*)(ws + off);   off = align(off + (size_t)M * 4);
    int*   excl   = (int*)(ws + off);   off = align(off + (size_t)M * 4);
    int*   bsum   = (int*)(ws + off);   off = align(off + (size_t)256 * 4);
    int*   rowptr = (int*)(ws + off);   off = align(off + (size_t)(N + 1) * 4);
    int*   gstart = (int*)(ws + off);   off = align(off + (size_t)(G + 1) * 4);
    float* dinv   = (float*)(ws + off); off = align(off + (size_t)N * 4);
    float* pooled = (float*)(ws + off); off = align(off + (size_t)G * HDIM * 4);
    unsigned short* wsw1 = (unsigned short*)(ws + off); off = align(off + (size_t)16384 * 2);
    unsigned short* wsw2 = (unsigned short*)(ws + off); off = align(off + (size_t)16384 * 2);
    float* pb1    = (float*)(ws + off); off = align(off + (size_t)128 * 4);
    float* pb2    = (float*)(ws + off); off = align(off + (size_t)128 * 4);
    unsigned int* packed = (unsigned int*)(ws + off); off = align(off + (size_t)E * 4);
    int*   col    = (int*)(ws + off);   off = align(off + (size_t)E * 4);
    unsigned int* bufA = (unsigned int*)(ws + off); off = align(off + (size_t)N * 32 * 4);  // fp8 N x 128 (P-order)
    unsigned int* bufB = (unsigned int*)(ws + off); off = align(off + (size_t)N * 64 * 4);  // bf16 N x 128 (P-order)
    (void)ws_size;

    const int blkGemm = (N + 63) / 64;
    const int blkGather = (N + 7) / 8;            // half-wave per node, 8 nodes/block
    const int blkPool = (N + PCH - 1) / PCH;

    // ---- binning -> CSR + dinv (no global atomics) + weight/bias prep ----
    block_hist<<<NBLK, 256, 0, stream>>>(dst, hist, E, NB);
    scanA<<<nscanA, 256, 0, stream>>>(hist, excl, bsum, M, NB, NBLK);
    scanB<<<1, 256, 0, stream>>>(bsum, nscanA);
    bucket_scatter<<<NBLK, 256, 0, stream>>>(src, dst, excl, bsum, packed, E, NB, NBLK);
    bucket_to_csr<<<NB, 256, 0, stream>>>(packed, excl, bsum, rowptr, dinv, col, E, N, NB, NBLK);
    setup_misc<<<3, 256, 0, stream>>>(W1, W2, b1, b2, wsw1, wsw2, pb1, pb2,
                                      batch, gstart, pooled, N, G);

    // ---- layer 1 (fp32 in, fp8 P-order out) ----
    gemm_mfma<false><<<blkGemm, 256, 0, stream>>>(x, wsw1, dinv, bufA, N);
    gather_fused<<<blkGather, 256, 0, stream>>>(bufA, rowptr, col, dinv, pb1,
                                                (uint2*)bufB, N);

    // ---- layer 2 (bf16 P-order in, fp8 P-order out) ----
    gemm_mfma<true><<<blkGemm, 256, 0, stream>>>(bufB, wsw2, dinv, bufA, N);
    gather_fused<<<blkGather, 256, 0, stream>>>(bufA, rowptr, col, dinv, pb2,
                                                (uint2*)bufB, N);

    // ---- pool + heads ----
    pool_partial<<<blkPool, 256, 0, stream>>>((const unsigned short*)bufB, batch, pooled, N);
    head_kernel<<<G, 64, 0, stream>>>(pooled, gstart, Wa, ba, Wv, bv, log_std, out, G);
}

// Round 11
// 332.511 us; speedup vs baseline: 9.4580x; 1.0752x over previous
//
#include <hip/hip_runtime.h>
#include <hip/hip_bf16.h>

#define FDIM 128
#define HDIM 128
#define ADIM 32
#define PCH 128      // rows per pool block
#define BSH 6        // bucket shift: 64 dst nodes per bucket
#define BWD 64
#define CHUNK 8192   // edges per binning block
#define MAXNB 2048   // max buckets supported (N <= 131072)

// Storage permutation for T'/H rows: byte position p holds col c(p).
// p = m15*8 + nt  <->  col = nt*16 + m15 ;  c(p) = ((p&7)<<4) | (p>>3)
#define CP(p) ((((p) & 7) << 4) | ((p) >> 3))

typedef short v8s __attribute__((ext_vector_type(8)));
typedef float v4f __attribute__((ext_vector_type(4)));
typedef float v2f __attribute__((ext_vector_type(2)));

// bf16x2 helpers (bitwise; bf16->fp32 exact, fp32->bf16 RNE)
static __device__ __forceinline__ float bflo(unsigned int u) {
    return __builtin_bit_cast(float, u << 16);
}
static __device__ __forceinline__ float bfhi(unsigned int u) {
    return __builtin_bit_cast(float, u & 0xffff0000u);
}
static __device__ __forceinline__ unsigned int bfpack(float a, float b) {
    unsigned int ua = __builtin_bit_cast(unsigned int, a);
    unsigned int ub = __builtin_bit_cast(unsigned int, b);
    ua += 0x7fffu + ((ua >> 16) & 1u);
    ub += 0x7fffu + ((ub >> 16) & 1u);
    return (ua >> 16) | (ub & 0xffff0000u);
}

// ---------------------------------------------------------------------------
// fp8 e4m3 (OCP) helpers. HW path: gfx950 cvt instructions.
#if defined(__has_builtin) && __has_builtin(__builtin_amdgcn_cvt_pk_f32_fp8) && \
    __has_builtin(__builtin_amdgcn_cvt_pk_fp8_f32)
#define FP8_HW 1
#endif

static __device__ __forceinline__ v2f fp8_dec_lo(unsigned int u) {
#ifdef FP8_HW
    return __builtin_amdgcn_cvt_pk_f32_fp8(u, false);
#else
    v2f r;
    #pragma unroll
    for (int i = 0; i < 2; ++i) {
        unsigned b = (u >> (8 * i)) & 0xffu;
        unsigned s = b >> 7, e = (b >> 3) & 0xfu, m = b & 7u;
        float v = (e == 0) ? (float)m * 0.001953125f
                           : __builtin_bit_cast(float, ((e + 120u) << 23) | (m << 20));
        r[i] = s ? -v : v;
    }
    return r;
#endif
}
static __device__ __forceinline__ v2f fp8_dec_hi(unsigned int u) {
#ifdef FP8_HW
    return __builtin_amdgcn_cvt_pk_f32_fp8(u, true);
#else
    return fp8_dec_lo(u >> 16);
#endif
}

#ifndef FP8_HW
static __device__ __forceinline__ unsigned int fp8_enc1(float x) {
    unsigned s = __builtin_bit_cast(unsigned, x) >> 31;
    float ax = fabsf(x);
    if (ax > 448.f) return (s << 7) | 0x7Eu;
    if (ax < 0.0009765625f) return s << 7;
    int e2 = (int)((__builtin_bit_cast(unsigned, ax) >> 23) & 0xff) - 127;
    int qe = (e2 < -6 ? -6 : e2) - 3;
    float q = __builtin_bit_cast(float, (unsigned)((qe + 127) << 23));
    float r = rintf(ax / q) * q;
    if (r > 448.f) return (s << 7) | 0x7Eu;
    if (r < 0.001953125f) return s << 7;
    unsigned ub = __builtin_bit_cast(unsigned, r);
    int re = (int)((ub >> 23) & 0xff) - 127;
    if (re < -6) {
        unsigned m = (unsigned)rintf(r * 512.f);
        return (s << 7) | m;
    }
    return (s << 7) | ((unsigned)(re + 7) << 3) | ((ub >> 20) & 7u);
}
#endif

// pack 4 floats -> 4 fp8 bytes in one dword (byte i = value i)
static __device__ __forceinline__ unsigned int fp8x4_enc(float a, float b, float c, float d) {
#ifdef FP8_HW
    int p = __builtin_amdgcn_cvt_pk_fp8_f32(a, b, 0, false);
    p = __builtin_amdgcn_cvt_pk_fp8_f32(c, d, p, true);
    return (unsigned int)p;
#else
    return fp8_enc1(a) | (fp8_enc1(b) << 8) | (fp8_enc1(c) << 16) | (fp8_enc1(d) << 24);
#endif
}

// ---------------------------------------------------------------------------
// Per-block LDS bucket histogram (blocks < NBLK) + fused one-off setup work
// (blocks NBLK..NBLK+2): weight/bias prep, graph bounds, pooled zero.
__global__ __launch_bounds__(256) void block_hist_setup(const int* __restrict__ dst,
                                                        int* __restrict__ hist,  // [nblk][NB]
                                                        int E, int NB, int NBLK,
                                                        const float* __restrict__ W1,
                                                        const float* __restrict__ W2,
                                                        const float* __restrict__ b1,
                                                        const float* __restrict__ b2,
                                                        unsigned short* __restrict__ wsw1,
                                                        unsigned short* __restrict__ wsw2,
                                                        float* __restrict__ pb1,
                                                        float* __restrict__ pb2,
                                                        const int* __restrict__ batch,
                                                        int* __restrict__ gstart,
                                                        float* __restrict__ pooled,
                                                        int n, int G) {
    __shared__ int h[MAXNB];
    const int tid = threadIdx.x;
    if (blockIdx.x >= (unsigned)NBLK) {
        const int role = blockIdx.x - NBLK;
        if (role == 0) {
            for (int idx = tid; idx < 16384; idx += 256) {
                int nn = idx >> 7, k = idx & 127;
                wsw1[idx] = (unsigned short)(bfpack(W1[k * 128 + nn], 0.f) & 0xffffu);
                wsw2[idx] = (unsigned short)(bfpack(W2[CP(k) * 128 + nn], 0.f) & 0xffffu);
            }
            if (tid < 128) {
                pb1[tid] = b1[CP(tid)];
                pb2[tid] = b2[CP(tid)];
            }
        } else if (role == 1) {
            if (tid <= G) {
                int lo = 0, hi = n;
                while (lo < hi) { int mid = (lo + hi) >> 1; if (batch[mid] < tid) lo = mid + 1; else hi = mid; }
                gstart[tid] = lo;
            }
        } else {
            for (int i = tid; i < G * 128; i += 256) pooled[i] = 0.f;
        }
        return;
    }
    for (int i = tid; i < NB; i += 256) h[i] = 0;
    __syncthreads();
    const int base = blockIdx.x * CHUNK;
    int lim = base + CHUNK; if (lim > E) lim = E;
    for (int i = base + tid; i < lim; i += 256) atomicAdd(&h[dst[i] >> BSH], 1);
    __syncthreads();
    int* hrow = hist + (size_t)blockIdx.x * NB;
    for (int b = tid; b < NB; b += 256) hrow[b] = h[b];
}

// Exclusive scan over M = NB*NBLK counts in bucket-major order.
__global__ void scanA(const int* __restrict__ hist, int* __restrict__ excl,
                      int* __restrict__ bsum, int M, int NB, int NBLK) {
    __shared__ int tmp[256];
    const int t = threadIdx.x;
    const int idx = blockIdx.x * 2048 + t * 8;
    int v[8], s = 0;
    #pragma unroll
    for (int i = 0; i < 8; ++i) {
        int p = idx + i;
        v[i] = (p < M) ? hist[(size_t)(p % NBLK) * NB + (p / NBLK)] : 0;
        s += v[i];
    }
    tmp[t] = s;
    __syncthreads();
    for (int off = 1; off < 256; off <<= 1) {
        int x = (t >= off) ? tmp[t - off] : 0;
        __syncthreads();
        tmp[t] += x;
        __syncthreads();
    }
    int run = tmp[t] - s;
    #pragma unroll
    for (int i = 0; i < 8; ++i) {
        int p = idx + i;
        if (p < M) excl[p] = run;
        run += v[i];
    }
    if (t == 255) bsum[blockIdx.x] = tmp[255];
}

__global__ void scanB(int* __restrict__ bsum, int nb) {
    __shared__ int tmp[256];
    const int t = threadIdx.x;
    int s = (t < nb) ? bsum[t] : 0;
    tmp[t] = s;
    __syncthreads();
    for (int off = 1; off < 256; off <<= 1) {
        int x = (t >= off) ? tmp[t - off] : 0;
        __syncthreads();
        tmp[t] += x;
        __syncthreads();
    }
    if (t < nb) bsum[t] = tmp[t] - s;
}

// Re-read edges; exact LDS cursors from scanned hist (+bsum fixup folded in);
// write packed edge (src | node-in-bucket<<26) grouped by bucket.
__global__ __launch_bounds__(256) void bucket_scatter(const int* __restrict__ src,
                                                      const int* __restrict__ dst,
                                                      const int* __restrict__ excl,
                                                      const int* __restrict__ bsum,
                                                      unsigned int* __restrict__ packed,
                                                      int E, int NB, int NBLK) {
    __shared__ int cur[MAXNB];
    const int tid = threadIdx.x;
    const int blk = blockIdx.x;
    for (int b = tid; b < NB; b += 256) {
        size_t p = (size_t)b * NBLK + blk;
        cur[b] = excl[p] + bsum[p >> 11];
    }
    __syncthreads();
    const int base = blk * CHUNK;
    int lim = base + CHUNK; if (lim > E) lim = E;
    for (int i = base + tid; i < lim; i += 256) {
        int d = dst[i];
        int s = src[i];
        int pos = atomicAdd(&cur[d >> BSH], 1);  // LDS atomic only
        packed[pos] = (unsigned)s | ((unsigned)(d & (BWD - 1)) << 26);
    }
}

// One block per bucket: in-bucket per-node counts -> rowptr + dinv + node-grouped col.
__global__ __launch_bounds__(256) void bucket_to_csr(const unsigned int* __restrict__ packed,
                                                     const int* __restrict__ excl,
                                                     const int* __restrict__ bsum,
                                                     int* __restrict__ rowptr,
                                                     float* __restrict__ dinv,
                                                     int* __restrict__ col,
                                                     int E, int N, int NB, int NBLK) {
    __shared__ int cnt[BWD];
    __shared__ int offs[BWD];
    const int b = blockIdx.x;
    const int tid = threadIdx.x;
    size_t p0 = (size_t)b * NBLK;
    const int base = excl[p0] + bsum[p0 >> 11];
    int next;
    if (b + 1 < NB) {
        size_t p1 = (size_t)(b + 1) * NBLK;
        next = excl[p1] + bsum[p1 >> 11];
    } else {
        next = E;
    }
    if (tid < BWD) cnt[tid] = 0;
    __syncthreads();
    for (int i = base + tid; i < next; i += 256) atomicAdd(&cnt[packed[i] >> 26], 1);
    __syncthreads();
    if (tid == 0) {
        int run = 0;
        for (int j = 0; j < BWD; ++j) { offs[j] = run; run += cnt[j]; }
    }
    __syncthreads();
    if (tid < BWD) {
        int node = (b << BSH) + tid;
        if (node < N) {
            rowptr[node] = base + offs[tid];
            dinv[node] = rsqrtf((float)cnt[tid] + 1.0f);
        }
        cnt[tid] = offs[tid];  // reuse as in-bucket cursors
    }
    if (b == NB - 1 && tid == 0) rowptr[N] = E;
    __syncthreads();
    for (int i = base + tid; i < next; i += 256) {
        unsigned int u = packed[i];
        int j = u >> 26;
        int pos = base + atomicAdd(&cnt[j], 1);  // LDS atomic only
        col[pos] = (int)(u & 0x03ffffffu);
    }
}

// ---------------------------------------------------------------------------
// LDS-free MFMA GEMM: Out[r] = fp8((X[r] @ W) * rowscale[r]), cols in P-order.
// X has zero intra-block reuse -> each wave loads its 16 rows' A-fragments
// DIRECTLY from global (per instr: 16 rows x one full 128B line, 100% line
// utilization). W fragments register-double-buffered from L1-resident wsw.
// No LDS, no barrier -> waves fully independent.
// Layouts (m89/m120-verified): A: m=lane&15, k=quad*8+j. B: n=lane&15,
// k=quad*8+j. C/D: col=lane&15, row=quad*4+reg.
template <bool BF16IN>
__global__ __launch_bounds__(256, 4) void gemm_mfma(const void* __restrict__ Xv,
                                                    const unsigned short* __restrict__ wsw,
                                                    const float* __restrict__ rowscale,
                                                    uint2* __restrict__ Out, int n) {
    const int tid = threadIdx.x;
    const int w = tid >> 6;
    const int lane = tid & 63;
    const int q = lane >> 4;
    const int m15 = lane & 15;
    const int rbase = blockIdx.x * 64;

    const int arow = rbase + w * 16 + m15;
    const int srow = (arow < n) ? arow : (n - 1);  // clamped; garbage rows never stored

    // A fragments straight from global
    v8s a[4];
    if (BF16IN) {
        const unsigned short* xr = (const unsigned short*)Xv + (size_t)srow * 128 + q * 8;
        #pragma unroll
        for (int kk = 0; kk < 4; ++kk)
            a[kk] = __builtin_bit_cast(v8s, *(const uint4*)(xr + kk * 32));
    } else {
        const float* xr = (const float*)Xv + (size_t)srow * 128 + q * 8;
        #pragma unroll
        for (int kk = 0; kk < 4; ++kk) {
            float4 v0 = *(const float4*)(xr + kk * 32);
            float4 v1 = *(const float4*)(xr + kk * 32 + 4);
            uint4 p;
            p.x = bfpack(v0.x, v0.y); p.y = bfpack(v0.z, v0.w);
            p.z = bfpack(v1.x, v1.y); p.w = bfpack(v1.z, v1.w);
            a[kk] = __builtin_bit_cast(v8s, p);
        }
    }

    // W fragments: register double-buffer (prefetch nt+1 during nt's MFMAs)
    const v8s* __restrict__ pW = (const v8s*)wsw;  // fragment idx = row*16 + kk*4 + q
    v8s bcur[4], bnxt[4];
    #pragma unroll
    for (int kk = 0; kk < 4; ++kk) bcur[kk] = pW[(size_t)m15 * 16 + kk * 4 + q];

    v4f acc[8];
    #pragma unroll
    for (int nt = 0; nt < 8; ++nt) acc[nt] = (v4f){0.f, 0.f, 0.f, 0.f};

    #pragma unroll
    for (int nt = 0; nt < 8; ++nt) {
        if (nt < 7) {
            #pragma unroll
            for (int kk = 0; kk < 4; ++kk)
                bnxt[kk] = pW[(size_t)((nt + 1) * 16 + m15) * 16 + kk * 4 + q];
        }
        #pragma unroll
        for (int kk = 0; kk < 4; ++kk)
            acc[nt] = __builtin_amdgcn_mfma_f32_16x16x32_bf16(a[kk], bcur[kk], acc[nt], 0, 0, 0);
        #pragma unroll
        for (int kk = 0; kk < 4; ++kk) bcur[kk] = bnxt[kk];
    }

    // epilogue: D row = q*4+reg, col = nt*16+m15 -> P-order bytes p=m15*8+nt
    #pragma unroll
    for (int reg = 0; reg < 4; ++reg) {
        int row = rbase + w * 16 + q * 4 + reg;
        if (row < n) {
            float sc = rowscale[row];
            unsigned int d0 = fp8x4_enc(acc[0][reg] * sc, acc[1][reg] * sc,
                                        acc[2][reg] * sc, acc[3][reg] * sc);
            unsigned int d1 = fp8x4_enc(acc[4][reg] * sc, acc[5][reg] * sc,
                                        acc[6][reg] * sc, acc[7][reg] * sc);
            Out[(size_t)row * 16 + m15] = make_uint2(d0, d1);
        }
    }
}

// ---------------------------------------------------------------------------
// Fused CSR gather + epilogue on pre-scaled fp8 T' (P-ordered rows):
//   h[d] = relu( (sum_{s in in(d)} T'[s] + T'[d]) * dinv[d] + pbias )
// HALF-wave per dst node (32 lanes x 1 dword = 128 B row): no cross-lane
// combine; v2f accumulators -> v_pk_add_f32; int2 col loads (even-aligned).
__global__ __launch_bounds__(256) void gather_fused(const unsigned int* __restrict__ T32,
                                                    const int* __restrict__ rowptr,
                                                    const int* __restrict__ col,
                                                    const float* __restrict__ dinv,
                                                    const float* __restrict__ pbias,
                                                    uint2* __restrict__ H, int n) {
    const int wave = (blockIdx.x * 256 + threadIdx.x) >> 6;
    const int d = wave * 2 + ((threadIdx.x >> 5) & 1);
    const int hl = threadIdx.x & 31;
    if (d >= n) return;
    int e = rowptr[d];
    const int end = rowptr[d + 1];

    v2f sl0 = {0.f, 0.f}, sh0 = {0.f, 0.f}, sl1 = {0.f, 0.f}, sh1 = {0.f, 0.f};

    if ((e & 1) && e < end) {  // peel to even alignment for int2 col loads
        unsigned int u = T32[(size_t)col[e] * 32 + hl];
        sl0 += fp8_dec_lo(u); sh0 += fp8_dec_hi(u);
        ++e;
    }
    for (; e + 7 < end; e += 8) {
        int2 p01 = *(const int2*)(col + e);
        int2 p23 = *(const int2*)(col + e + 2);
        int2 p45 = *(const int2*)(col + e + 4);
        int2 p67 = *(const int2*)(col + e + 6);
        unsigned int u0 = T32[(size_t)p01.x * 32 + hl];
        unsigned int u1 = T32[(size_t)p01.y * 32 + hl];
        unsigned int u2 = T32[(size_t)p23.x * 32 + hl];
        unsigned int u3 = T32[(size_t)p23.y * 32 + hl];
        unsigned int u4 = T32[(size_t)p45.x * 32 + hl];
        unsigned int u5 = T32[(size_t)p45.y * 32 + hl];
        unsigned int u6 = T32[(size_t)p67.x * 32 + hl];
        unsigned int u7 = T32[(size_t)p67.y * 32 + hl];
        sl0 += fp8_dec_lo(u0); sh0 += fp8_dec_hi(u0);
        sl1 += fp8_dec_lo(u1); sh1 += fp8_dec_hi(u1);
        sl0 += fp8_dec_lo(u2); sh0 += fp8_dec_hi(u2);
        sl1 += fp8_dec_lo(u3); sh1 += fp8_dec_hi(u3);
        sl0 += fp8_dec_lo(u4); sh0 += fp8_dec_hi(u4);
        sl1 += fp8_dec_lo(u5); sh1 += fp8_dec_hi(u5);
        sl0 += fp8_dec_lo(u6); sh0 += fp8_dec_hi(u6);
        sl1 += fp8_dec_lo(u7); sh1 += fp8_dec_hi(u7);
    }
    for (; e + 1 < end; e += 2) {
        int2 p = *(const int2*)(col + e);
        unsigned int u0 = T32[(size_t)p.x * 32 + hl];
        unsigned int u1 = T32[(size_t)p.y * 32 + hl];
        sl0 += fp8_dec_lo(u0); sh0 += fp8_dec_hi(u0);
        sl1 += fp8_dec_lo(u1); sh1 += fp8_dec_hi(u1);
    }
    if (e < end) {
        unsigned int u = T32[(size_t)col[e] * 32 + hl];
        sl0 += fp8_dec_lo(u); sh0 += fp8_dec_hi(u);
    }

    // self term
    unsigned int su = T32[(size_t)d * 32 + hl];
    sl0 += fp8_dec_lo(su); sh0 += fp8_dec_hi(su);
    v2f sl = sl0 + sl1, sh = sh0 + sh1;

    const float di = dinv[d];
    const float4 bv = ((const float4*)pbias)[hl];
    float o0 = fmaxf(fmaf(sl.x, di, bv.x), 0.f);
    float o1 = fmaxf(fmaf(sl.y, di, bv.y), 0.f);
    float o2 = fmaxf(fmaf(sh.x, di, bv.z), 0.f);
    float o3 = fmaxf(fmaf(sh.y, di, bv.w), 0.f);
    uint2 o;
    o.x = bfpack(o0, o1);
    o.y = bfpack(o2, o3);
    H[(size_t)d * 32 + hl] = o;
}

// ---------------------------------------------------------------------------
// Parallel partial-sum pool over bf16 h (P-ordered; pooled P-ordered), bf16x2
// vectorized: thread covers 2 cols, 4 row-lanes per block.
__global__ __launch_bounds__(256) void pool_partial(const unsigned int* __restrict__ h2,
                                                    const int* __restrict__ batch,
                                                    float* __restrict__ pooled, int n) {
    const int c = threadIdx.x & 63;       // cols 2c, 2c+1
    const int rl = threadIdx.x >> 6;      // 0..3
    int r = blockIdx.x * PCH + rl;
    int rend = blockIdx.x * PCH + PCH;
    if (rend > n) rend = n;
    v2f acc = {0.f, 0.f};
    int cur = -1;
    for (; r < rend; r += 4) {
        int g = batch[r];
        if (g != cur) {
            if (cur >= 0) {
                atomicAdd(&pooled[(size_t)cur * 128 + 2 * c], acc.x);
                atomicAdd(&pooled[(size_t)cur * 128 + 2 * c + 1], acc.y);
            }
            acc = (v2f){0.f, 0.f};
            cur = g;
        }
        unsigned int u = h2[(size_t)r * 64 + c];
        acc.x += bflo(u);
        acc.y += bfhi(u);
    }
    if (cur >= 0) {
        atomicAdd(&pooled[(size_t)cur * 128 + 2 * c], acc.x);
        atomicAdd(&pooled[(size_t)cur * 128 + 2 * c + 1], acc.y);
    }
}

// ---------------------------------------------------------------------------
// out layout: [G*A action_mean][A std][G value]. pooled is P-ordered ->
// index head weights by c(p).
__global__ void head_kernel(const float* __restrict__ pooled, const int* __restrict__ gstart,
                            const float* __restrict__ Wa, const float* __restrict__ ba,
                            const float* __restrict__ Wv, const float* __restrict__ bv,
                            const float* __restrict__ log_std, float* __restrict__ out, int G) {
    int g = blockIdx.x;
    int t = threadIdx.x;  // 64
    __shared__ float sp[128];
    float inv = 1.0f / fmaxf((float)(gstart[g + 1] - gstart[g]), 1.0f);
    sp[t] = pooled[(size_t)g * 128 + t] * inv;
    sp[t + 64] = pooled[(size_t)g * 128 + 64 + t] * inv;
    __syncthreads();
    if (t < 32) {
        float s = 0.f;
        #pragma unroll 8
        for (int k = 0; k < 128; ++k) s = fmaf(sp[k], Wa[CP(k) * ADIM + t], s);
        out[g * ADIM + t] = s + ba[t];
        if (g == 0) out[G * ADIM + t] = expf(log_std[t]);
    } else if (t == 32) {
        float s = 0.f;
        #pragma unroll 8
        for (int k = 0; k < 128; ++k) s = fmaf(sp[k], Wv[CP(k)], s);
        out[G * ADIM + ADIM + g] = s + bv[0];
    }
}

// ---------------------------------------------------------------------------
extern "C" void kernel_launch(void* const* d_in, const int* in_sizes, int n_in,
                              void* d_out, int out_size, void* d_ws, size_t ws_size,
                              hipStream_t stream) {
    const float* x       = (const float*)d_in[0];
    const int*   ei      = (const int*)d_in[1];
    const int*   batch   = (const int*)d_in[2];
    const float* W1      = (const float*)d_in[3];
    const float* b1      = (const float*)d_in[4];
    const float* W2      = (const float*)d_in[5];
    const float* b2      = (const float*)d_in[6];
    const float* Wa      = (const float*)d_in[7];
    const float* ba      = (const float*)d_in[8];
    const float* Wv      = (const float*)d_in[9];
    const float* bv      = (const float*)d_in[10];
    const float* log_std = (const float*)d_in[11];
    float* out = (float*)d_out;

    const int N = in_sizes[0] / FDIM;
    const int E = in_sizes[1] / 2;
    const int G = (out_size - ADIM) / (ADIM + 1);
    const int NB = (N + BWD - 1) >> BSH;          // buckets (<= MAXNB for N <= 131072)
    const int NBLK = (E + CHUNK - 1) / CHUNK;     // binning blocks
    const int M = NB * NBLK;                      // scan length
    const int nscanA = (M + 2047) / 2048;         // <= 256

    const int* src = ei;
    const int* dst = ei + E;

    auto align = [](size_t v) { return (v + 255) & ~(size_t)255; };
    char* ws = (char*)d_ws;
    size_t off = 0;
    int*   hist   = (int*)(ws + off);   off = align(off + (size_t)M * 4);
    int*   excl   = (int*)(ws + off);   off = align(off + (size_t)M * 4);
    int*   bsum   = (int*)(ws + off);   off = align(off + (size_t)256 * 4);
    int*   rowptr = (int*)(ws + off);   off = align(off + (size_t)(N + 1) * 4);
    int*   gstart = (int*)(ws + off);   off = align(off + (size_t)(G + 1) * 4);
    float* dinv   = (float*)(ws + off); off = align(off + (size_t)N * 4);
    float* pooled = (float*)(ws + off); off = align(off + (size_t)G * HDIM * 4);
    unsigned short* wsw1 = (unsigned short*)(ws + off); off = align(off + (size_t)16384 * 2);
    unsigned short* wsw2 = (unsigned short*)(ws + off); off = align(off + (size_t)16384 * 2);
    float* pb1    = (float*)(ws + off); off = align(off + (size_t)128 * 4);
    float* pb2    = (float*)(ws + off); off = align(off + (size_t)128 * 4);
    unsigned int* packed = (unsigned int*)(ws + off); off = align(off + (size_t)E * 4);
    int*   col    = (int*)(ws + off);   off = align(off + (size_t)E * 4);
    unsigned int* bufA = (unsigned int*)(ws + off); off = align(off + (size_t)N * 32 * 4);  // fp8 N x 128 (P-order)
    unsigned int* bufB = (unsigned int*)(ws + off); off = align(off + (size_t)N * 64 * 4);  // bf16 N x 128 (P-order)
    (void)ws_size;

    const int blkGemm = (N + 63) / 64;
    const int blkGather = (N + 7) / 8;            // half-wave per node, 8 nodes/block
    const int blkPool = (N + PCH - 1) / PCH;

    // ---- binning -> CSR + dinv (no global atomics); setup fused in ----
    block_hist_setup<<<NBLK + 3, 256, 0, stream>>>(dst, hist, E, NB, NBLK,
                                                   W1, W2, b1, b2, wsw1, wsw2, pb1, pb2,
                                                   batch, gstart, pooled, N, G);
    scanA<<<nscanA, 256, 0, stream>>>(hist, excl, bsum, M, NB, NBLK);
    scanB<<<1, 256, 0, stream>>>(bsum, nscanA);
    bucket_scatter<<<NBLK, 256, 0, stream>>>(src, dst, excl, bsum, packed, E, NB, NBLK);
    bucket_to_csr<<<NB, 256, 0, stream>>>(packed, excl, bsum, rowptr, dinv, col, E, N, NB, NBLK);

    // ---- layer 1 (fp32 in, fp8 P-order out) ----
    gemm_mfma<false><<<blkGemm, 256, 0, stream>>>(x, wsw1, dinv, (uint2*)bufA, N);
    gather_fused<<<blkGather, 256, 0, stream>>>(bufA, rowptr, col, dinv, pb1,
                                                (uint2*)bufB, N);

    // ---- layer 2 (bf16 P-order in, fp8 P-order out) ----
    gemm_mfma<true><<<blkGemm, 256, 0, stream>>>(bufB, wsw2, dinv, (uint2*)bufA, N);
    gather_fused<<<blkGather, 256, 0, stream>>>(bufA, rowptr, col, dinv, pb2,
                                                (uint2*)bufB, N);

    // ---- pool + heads ----
    pool_partial<<<blkPool, 256, 0, stream>>>(bufB, batch, pooled, N);
    head_kernel<<<G, 64, 0, stream>>>(pooled, gstart, Wa, ba, Wv, bv, log_std, out, G);
}